// Round 1
// baseline (230.569 us; speedup 1.0000x reference)
//
#include <hip/hip_runtime.h>
#include <math.h>

#define NEG_INF (-__builtin_inff())

typedef __attribute__((ext_vector_type(8))) short short8;
typedef __attribute__((ext_vector_type(4))) float f32x4;

__device__ __forceinline__ unsigned f2bf(float f) {   // fp32 -> bf16 bits (RNE)
    union { float f; unsigned u; } v; v.f = f;
    return (v.u + 0x7fffu + ((v.u >> 16) & 1u)) >> 16;
}

// ============ pad kernel: x channel -> zero-padded (4,66,66,66) bf16 ============
// Padded cell (z,y,x) = volume voxel (z-1,y-1,x-1); pad ring = 0 (conv SAME).
__global__ __launch_bounds__(256) void pad_kernel(
    const float* __restrict__ img, unsigned short* __restrict__ pad)
{
    int i = blockIdx.x * 256 + threadIdx.x;      // cell within one sample
    if (i >= 66 * 66 * 66) return;
    int b = blockIdx.y;
    int z = i / 4356;
    int rem = i - z * 4356;
    int y = rem / 66;
    int x = rem - y * 66;
    float v = 0.f;
    if (z >= 1 && z <= 64 && y >= 1 && y <= 64 && x >= 1 && x <= 64)
        v = img[((size_t)b << 19) + ((z - 1) << 12) + ((y - 1) << 6) + (x - 1)];
    pad[(size_t)b * 287496 + i] = (unsigned short)f2bf(v);
}

// ============ gate via MFMA: p = sigmoid(sum_c pw[c]*relu(conv(x)+hb[c])) ======
// GEMM: A[m=voxel][k=tap] * B[k][n=channel]; K=27 taps + bias row (k=27, A=1.0,
// B=hb) padded to 32; N=150 padded to 160 (10 tiles). 16x16x32 bf16 MFMA.
// A frag: lane holds A[m=lane&15][k=(lane>>4)*8+j]; B: B[k=(lane>>4)*8+j][n=lane&15];
// D: col=lane&15, row=(lane>>4)*4+reg.
// Grid 2048 (8 groups/wave): 8 blocks/CU -> 32 waves/CU for latency hiding.
__global__ __launch_bounds__(256, 4) void gate_mfma(
    const unsigned short* __restrict__ pad,
    const float* __restrict__ hw, const float* __restrict__ hb,
    const float* __restrict__ pw, float* __restrict__ p)
{
    const int lane = threadIdx.x & 63;
    const int col  = lane & 15;          // B: channel-in-tile; A: voxel m
    const int q    = lane >> 4;
    const int W    = blockIdx.x * 4 + (threadIdx.x >> 6);   // 8192 waves

    // ---- B fragments + pw, built once per wave
    int4  bfrag[10];
    float pwv[10];
    #pragma unroll
    for (int t = 0; t < 10; ++t) {
        int c = 16 * t + col;
        bool cv = c < 150;
        unsigned hv[8];
        #pragma unroll
        for (int j = 0; j < 8; ++j) {
            int k = 8 * q + j;
            float wv = 0.f;
            if (cv) {
                if (k < 27) wv = hw[c * 27 + k];
                else if (k == 27) wv = hb[c];
            }
            hv[j] = f2bf(wv);
        }
        bfrag[t] = make_int4(hv[0] | (hv[1] << 16), hv[2] | (hv[3] << 16),
                             hv[4] | (hv[5] << 16), hv[6] | (hv[7] << 16));
        pwv[t] = cv ? pw[c] : 0.f;
    }

    // ---- per-lane A-tap offsets into padded volume (loop-invariant)
    int offL[8]; unsigned cstA[8]; bool ldA[8];
    #pragma unroll
    for (int j = 0; j < 8; ++j) {
        int k = 8 * q + j;
        int dz = (k * 57) >> 9;          // k/9 for k<32
        int rem = k - 9 * dz;
        int dy = (rem * 171) >> 9;       // rem/3
        int dx = rem - 3 * dy;
        ldA[j]  = (k < 27);
        offL[j] = (k < 27) ? (dz * 4356 + dy * 66 + dx) : 0;
        cstA[j] = (k == 27) ? 0x3F80u : 0u;   // bias row: bf16(1.0)
    }

    // ---- 8 groups of 16 voxels per wave (unroll 2: next loads under reduce)
    #pragma unroll 2
    for (int i = 0; i < 8; ++i) {
        int g   = W * 8 + i;
        int x0  = (g & 3) << 4;
        int row = g >> 2;
        int y = row & 63, zz = (row >> 6) & 63, b = row >> 12;
        int abase = b * 287496 + zz * 4356 + y * 66 + x0 + col;

        unsigned av[8];
        #pragma unroll
        for (int j = 0; j < 8; ++j) {
            unsigned v = pad[abase + offL[j]];
            av[j] = ldA[j] ? v : cstA[j];
        }
        union { int4 i4; short8 s8; } af, bfu;
        af.i4 = make_int4(av[0] | (av[1] << 16), av[2] | (av[3] << 16),
                          av[4] | (av[5] << 16), av[6] | (av[7] << 16));

        const f32x4 zero = {0.f, 0.f, 0.f, 0.f};
        f32x4 rr[10];
        #pragma unroll
        for (int t = 0; t < 10; ++t) {
            bfu.i4 = bfrag[t];
            rr[t] = __builtin_amdgcn_mfma_f32_16x16x32_bf16(af.s8, bfu.s8, zero, 0, 0, 0);
        }
        float ax = 0.f, ay = 0.f, az = 0.f, aw = 0.f;
        #pragma unroll
        for (int t = 0; t < 10; ++t) {
            ax = fmaf(pwv[t], fmaxf(rr[t].x, 0.f), ax);
            ay = fmaf(pwv[t], fmaxf(rr[t].y, 0.f), ay);
            az = fmaf(pwv[t], fmaxf(rr[t].z, 0.f), az);
            aw = fmaf(pwv[t], fmaxf(rr[t].w, 0.f), aw);
        }
        #pragma unroll
        for (int m = 1; m < 16; m <<= 1) {
            ax += __shfl_xor(ax, m);
            ay += __shfl_xor(ay, m);
            az += __shfl_xor(az, m);
            aw += __shfl_xor(aw, m);
        }
        if (col == 0) {                  // rows 4q..4q+3 = x0+4q..x0+4q+3
            float4 o;
            o.x = 1.f / (1.f + __expf(-ax));
            o.y = 1.f / (1.f + __expf(-ay));
            o.z = 1.f / (1.f + __expf(-az));
            o.w = 1.f / (1.f + __expf(-aw));
            *(float4*)(p + (b << 18) + (zz << 12) + (y << 6) + x0 + 4 * q) = o;
        }
    }
}

// ============ fused propagation: in-place 40 KB LDS cube, compile-time T ======
// Cube 10z x 16y x 64x; output tile 2z x 8y x 64x (margins 4). Iteration it
// (lo=5-T+it) updates z,y in [lo, dim-lo); shrinking validity keeps it exact.
// Read phase -> registers, barrier, write phase, barrier. x-edge maxima via
// lane shuffles. Grid 1024 -> 4 blocks/CU -> 4 waves/SIMD (2x latency hiding
// vs the previous 48 KB / 2-block config; halo recompute is cheap since VALU
// utilization is ~12%).
#define ZC 10
#define YC 16
#define PL 1024   // 16*64 floats per z-plane

template<int T>
__global__ __launch_bounds__(256, 4) void prop_kernel(
    const float* __restrict__ vin, int sstride,
    const float* __restrict__ rimg,   // r base = img + 2^18, sample stride 2^19
    const float* __restrict__ pbuf,   // p, sample stride 2^18
    float* __restrict__ vout)
{
    __shared__ float S[ZC * PL];
    int blk = blockIdx.x;             // 1024 blocks: b(4) x tz(32) x ty(8)
    int b  = blk >> 8;
    int tz = ((blk >> 3) & 31) << 1;
    int ty = (blk & 7) << 3;

    const float* vb = vin  + (size_t)b * sstride;
    const float* rb = rimg + ((size_t)b << 19);
    const float* pb = pbuf + ((size_t)b << 18);
    float*       ob = vout + ((size_t)b << 18);

    int tid  = threadIdx.x;
    int x4   = tid & 15, x0 = x4 << 2;
    int yy   = tid >> 4;
    int lane = tid & 63;

    int gy = ty + yy - 4;
    bool vy = (unsigned)gy < 64u;

    // ---- stage
    {
        const float* src = vb + gy * 64 + x0;
        #pragma unroll
        for (int z = 0; z < ZC; ++z) {
            int gz = tz + z - 4;
            float4 v = make_float4(NEG_INF, NEG_INF, NEG_INF, NEG_INF);
            if (vy && ((unsigned)gz < 64u)) v = *(const float4*)(src + (gz << 12));
            *(float4*)(S + z * PL + yy * 64 + x0) = v;
        }
    }
    __syncthreads();

    int lbase = yy * 64 + x0;
    int goff  = gy * 64 + x0;

    // ROWY: vertical 3-row max (float4) + horizontal 3-window via shuffles
    #define ROWY(zz_, Q, C) {                                                  \
        const float* pz = S + (zz_) * PL + lbase;                              \
        float4 r0 = *(const float4*)(pz - 64);                                 \
        float4 r1 = *(const float4*)(pz);                                      \
        float4 r2 = *(const float4*)(pz + 64);                                 \
        float4 cm;                                                             \
        cm.x = fmaxf(fmaxf(r0.x, r1.x), r2.x);                                 \
        cm.y = fmaxf(fmaxf(r0.y, r1.y), r2.y);                                 \
        cm.z = fmaxf(fmaxf(r0.z, r1.z), r2.z);                                 \
        cm.w = fmaxf(fmaxf(r0.w, r1.w), r2.w);                                 \
        float lm = __shfl(cm.w, lane - 1);                                     \
        float rm = __shfl(cm.x, lane + 1);                                     \
        if (x4 == 0)  lm = NEG_INF;                                            \
        if (x4 == 15) rm = NEG_INF;                                            \
        Q.x = fmaxf(lm, fmaxf(cm.x, cm.y));                                    \
        Q.y = fmaxf(cm.x, fmaxf(cm.y, cm.z));                                  \
        Q.z = fmaxf(cm.y, fmaxf(cm.z, cm.w));                                  \
        Q.w = fmaxf(fmaxf(cm.z, cm.w), rm);                                    \
        C = r1;                                                                \
    }

    #pragma unroll
    for (int it = 0; it < T; ++it) {
        const int lo = 5 - T + it;
        bool act = (yy >= lo) && (yy < YC - lo);
        float4 vn[ZC - 2];
        if (act) {
            float4 q0, q1, q2, c1, c2, cd;
            ROWY(lo - 1, q0, cd);
            ROWY(lo,     q1, c1);
            #pragma unroll
            for (int z = lo; z < ZC - lo; ++z) {
                ROWY(z + 1, q2, c2);
                int gz = tz + z - 4;
                float4 r;
                if (vy && ((unsigned)gz < 64u)) {
                    int off = (gz << 12) + goff;
                    float4 pv = *(const float4*)(pb + off);
                    float4 rv = *(const float4*)(rb + off);
                    float4 m3;
                    m3.x = fmaxf(fmaxf(q0.x, q1.x), q2.x);
                    m3.y = fmaxf(fmaxf(q0.y, q1.y), q2.y);
                    m3.z = fmaxf(fmaxf(q0.z, q1.z), q2.z);
                    m3.w = fmaxf(fmaxf(q0.w, q1.w), q2.w);
                    r.x = fmaxf(c1.x, fmaf(pv.x, m3.x - rv.x, rv.x));
                    r.y = fmaxf(c1.y, fmaf(pv.y, m3.y - rv.y, rv.y));
                    r.z = fmaxf(c1.z, fmaf(pv.z, m3.z - rv.z, rv.z));
                    r.w = fmaxf(c1.w, fmaf(pv.w, m3.w - rv.w, rv.w));
                    if (it == T - 1) *(float4*)(ob + off) = r;
                } else {
                    r = c1;    // out-of-volume stays -inf / stale
                }
                vn[z - lo] = r;
                q0 = q1; q1 = q2; c1 = c2;
            }
        }
        __syncthreads();
        if (act) {
            #pragma unroll
            for (int z = lo; z < ZC - lo; ++z)
                *(float4*)(S + z * PL + lbase) = vn[z - lo];
        }
        __syncthreads();
    }
    #undef ROWY
}

extern "C" void kernel_launch(void* const* d_in, const int* in_sizes, int n_in,
                              void* d_out, int out_size, void* d_ws, size_t ws_size,
                              hipStream_t stream) {
    const float* img = (const float*)d_in[0];   // (4,2,64,64,64)
    const float* hw  = (const float*)d_in[1];   // (150,27)
    const float* hb  = (const float*)d_in[2];   // (150,)
    const float* pw  = (const float*)d_in[3];   // (150,)
    // d_in[4] = k (device scalar); reference fixes k=30.

    float* out = (float*)d_out;                      // X buffer (4 MB)
    float* p   = (float*)d_ws;                       // 4 MB
    float* vA  = (float*)((char*)d_ws + (4u << 20)); // Y buffer (4 MB)
    // padded bf16 volume (2.3 MB) shares the vA slot: used only before prop #1
    unsigned short* pad = (unsigned short*)((char*)d_ws + (4u << 20));

    pad_kernel<<<dim3(1124, 4), 256, 0, stream>>>(img, pad);
    gate_mfma<<<2048, 256, 0, stream>>>(pad, hw, hb, pw, p);

    const float* r0 = img + (1 << 18);  // r channel base, sample stride 2^19

    // 7*T4 + 1*T2 = 30 iterations; ping-pong ends in d_out.
    prop_kernel<4><<<1024, 256, 0, stream>>>(r0,  1 << 19, r0, p, vA);   // img -> Y
    prop_kernel<4><<<1024, 256, 0, stream>>>(vA,  1 << 18, r0, p, out);  // Y -> X
    prop_kernel<4><<<1024, 256, 0, stream>>>(out, 1 << 18, r0, p, vA);
    prop_kernel<4><<<1024, 256, 0, stream>>>(vA,  1 << 18, r0, p, out);
    prop_kernel<4><<<1024, 256, 0, stream>>>(out, 1 << 18, r0, p, vA);
    prop_kernel<4><<<1024, 256, 0, stream>>>(vA,  1 << 18, r0, p, out);
    prop_kernel<4><<<1024, 256, 0, stream>>>(out, 1 << 18, r0, p, vA);
    prop_kernel<2><<<1024, 256, 0, stream>>>(vA,  1 << 18, r0, p, out);  // -> d_out
}

// Round 2
// 219.576 us; speedup vs baseline: 1.0501x; 1.0501x over previous
//
#include <hip/hip_runtime.h>
#include <math.h>

#define NEG_INF (-__builtin_inff())

typedef __attribute__((ext_vector_type(8))) short short8;
typedef __attribute__((ext_vector_type(4))) float f32x4;

__device__ __forceinline__ unsigned f2bf(float f) {   // fp32 -> bf16 bits (RNE)
    union { float f; unsigned u; } v; v.f = f;
    return (v.u + 0x7fffu + ((v.u >> 16) & 1u)) >> 16;
}

// ============ pad kernel: x channel -> zero-padded (4,66,66,66) bf16 ============
// Padded cell (z,y,x) = volume voxel (z-1,y-1,x-1); pad ring = 0 (conv SAME).
__global__ __launch_bounds__(256) void pad_kernel(
    const float* __restrict__ img, unsigned short* __restrict__ pad)
{
    int i = blockIdx.x * 256 + threadIdx.x;      // cell within one sample
    if (i >= 66 * 66 * 66) return;
    int b = blockIdx.y;
    int z = i / 4356;
    int rem = i - z * 4356;
    int y = rem / 66;
    int x = rem - y * 66;
    float v = 0.f;
    if (z >= 1 && z <= 64 && y >= 1 && y <= 64 && x >= 1 && x <= 64)
        v = img[((size_t)b << 19) + ((z - 1) << 12) + ((y - 1) << 6) + (x - 1)];
    pad[(size_t)b * 287496 + i] = (unsigned short)f2bf(v);
}

// ============ gate via MFMA: p = sigmoid(sum_c pw[c]*relu(conv(x)+hb[c])) ======
// SWAPPED GEMM: D = W * X.  A[m=channel][k=tap] = weights (hb at k=27),
// B[k=tap][n=voxel] = data (1.0 at k=27).  K=28 padded to 32; channels 150
// padded to 160 (10 tiles of 16 rows). 16x16x32 bf16 MFMA.
// Both operand frags have layout idx=lane&15, k=(lane>>4)*8+j, so the fragment
// BUILD code is identical to the unswapped version; only the mfma arg order,
// pw indexing and epilogue change.
// D: col=lane&15 = voxel, row=4q+reg = channel-in-tile -> channel reduce is
// 3 in-lane adds + xor16 + xor32 (2 shuffles) instead of 4 serial hops.
__global__ __launch_bounds__(256, 4) void gate_mfma(
    const unsigned short* __restrict__ pad,
    const float* __restrict__ hw, const float* __restrict__ hb,
    const float* __restrict__ pw, float* __restrict__ p)
{
    const int lane = threadIdx.x & 63;
    const int col  = lane & 15;          // A: channel-in-tile; B: voxel n
    const int q    = lane >> 4;
    const int W    = blockIdx.x * 4 + (threadIdx.x >> 6);   // 4096 waves

    // ---- A fragments (weights) built once per wave
    int4 bfrag[10];
    #pragma unroll
    for (int t = 0; t < 10; ++t) {
        int c = 16 * t + col;
        bool cv = c < 150;
        unsigned hv[8];
        #pragma unroll
        for (int j = 0; j < 8; ++j) {
            int k = 8 * q + j;
            float wv = 0.f;
            if (cv) {
                if (k < 27) wv = hw[c * 27 + k];
                else if (k == 27) wv = hb[c];
            }
            hv[j] = f2bf(wv);
        }
        bfrag[t] = make_int4(hv[0] | (hv[1] << 16), hv[2] | (hv[3] << 16),
                             hv[4] | (hv[5] << 16), hv[6] | (hv[7] << 16));
    }
    // ---- pw per lane: D rows 4q+reg -> channel 16t+4q+r
    f32x4 pwq[10];
    #pragma unroll
    for (int t = 0; t < 10; ++t) {
        #pragma unroll
        for (int r = 0; r < 4; ++r) {
            int c = 16 * t + 4 * q + r;
            pwq[t][r] = (c < 150) ? pw[c] : 0.f;
        }
    }

    // ---- per-lane B-tap offsets into padded volume (loop-invariant)
    int offL[8]; unsigned cstA[8]; bool ldA[8];
    #pragma unroll
    for (int j = 0; j < 8; ++j) {
        int k = 8 * q + j;
        int dz = (k * 57) >> 9;          // k/9 for k<32
        int rem = k - 9 * dz;
        int dy = (rem * 171) >> 9;       // rem/3
        int dx = rem - 3 * dy;
        ldA[j]  = (k < 27);
        offL[j] = (k < 27) ? (dz * 4356 + dy * 66 + dx) : 0;
        cstA[j] = (k == 27) ? 0x3F80u : 0u;   // bias row: bf16(1.0)
    }

    // ---- 16 groups of 16 voxels per wave
    for (int i = 0; i < 16; ++i) {
        int g   = W * 16 + i;
        int x0  = (g & 3) << 4;
        int row = g >> 2;
        int y = row & 63, zz = (row >> 6) & 63, b = row >> 12;
        int abase = b * 287496 + zz * 4356 + y * 66 + x0 + col;

        unsigned av[8];
        #pragma unroll
        for (int j = 0; j < 8; ++j) {
            unsigned v = pad[abase + offL[j]];
            av[j] = ldA[j] ? v : cstA[j];
        }
        union { int4 i4; short8 s8; } af, bfu;
        af.i4 = make_int4(av[0] | (av[1] << 16), av[2] | (av[3] << 16),
                          av[4] | (av[5] << 16), av[6] | (av[7] << 16));

        const f32x4 zero = {0.f, 0.f, 0.f, 0.f};
        f32x4 rr[10];
        #pragma unroll
        for (int t = 0; t < 10; ++t) {
            bfu.i4 = bfrag[t];
            // A = weights, B = data  ->  D[channel][voxel]
            rr[t] = __builtin_amdgcn_mfma_f32_16x16x32_bf16(bfu.s8, af.s8, zero, 0, 0, 0);
        }
        float ax = 0.f, ay = 0.f, az = 0.f, aw = 0.f;
        #pragma unroll
        for (int t = 0; t < 10; ++t) {
            ax = fmaf(pwq[t].x, fmaxf(rr[t].x, 0.f), ax);
            ay = fmaf(pwq[t].y, fmaxf(rr[t].y, 0.f), ay);
            az = fmaf(pwq[t].z, fmaxf(rr[t].z, 0.f), az);
            aw = fmaf(pwq[t].w, fmaxf(rr[t].w, 0.f), aw);
        }
        // in-lane channel partials -> cross-q sum (2 shuffle hops)
        float s = (ax + ay) + (az + aw);
        s += __shfl_xor(s, 16);
        s += __shfl_xor(s, 32);
        if (lane < 16) {
            float o = 1.f / (1.f + __expf(-s));
            p[(b << 18) + (zz << 12) + (y << 6) + x0 + lane] = o;
        }
    }
}

// ============ fused propagation: in-place 48 KB LDS cube, compile-time T ======
// Cube 12z x 16y x 64x; output tile 4z x 8y x 64x (margins 4). Iteration it
// (lo=5-T+it) updates z,y in [lo, dim-lo); shrinking validity keeps it exact.
// NEW: 512 threads/block — bit 8 picks a z-half: h0 handles [lo,6), h1
// [6,12-lo). ZC=12/mid=6 makes the halves perfectly balanced at every it
// (spans 5/5,4/4,3/3,2/2). Same total work as the 256-thread version, half
// per thread -> 2 blocks/CU = 16 waves/CU = 4 waves/SIMD (2x latency hiding,
// zero extra halo). span is compile-time so vn[] stays statically indexed.
#define ZC 12
#define YC 16
#define PL 1024   // 16*64 floats per z-plane
#define ZMID 6

template<int T>
__global__ __launch_bounds__(512, 4) void prop_kernel(
    const float* __restrict__ vin, int sstride,
    const float* __restrict__ rimg,   // r base = img + 2^18, sample stride 2^19
    const float* __restrict__ pbuf,   // p, sample stride 2^18
    float* __restrict__ vout)
{
    __shared__ float S[ZC * PL];
    int blk = blockIdx.x;             // 512 blocks: b(4) x tz(16) x ty(8)
    int b  = blk >> 7;
    int tz = ((blk >> 3) & 15) << 2;
    int ty = (blk & 7) << 3;

    const float* vb = vin  + (size_t)b * sstride;
    const float* rb = rimg + ((size_t)b << 19);
    const float* pb = pbuf + ((size_t)b << 18);
    float*       ob = vout + ((size_t)b << 18);

    int tid  = threadIdx.x;
    int x4   = tid & 15, x0 = x4 << 2;
    int yy   = (tid >> 4) & 15;
    int h    = tid >> 8;              // z-half
    int lane = tid & 63;

    int gy = ty + yy - 4;
    bool vy = (unsigned)gy < 64u;

    // ---- stage: half h stages planes [6h, 6h+6)
    {
        const float* src = vb + gy * 64 + x0;
        #pragma unroll
        for (int zi = 0; zi < 6; ++zi) {
            int z  = 6 * h + zi;
            int gz = tz + z - 4;
            float4 v = make_float4(NEG_INF, NEG_INF, NEG_INF, NEG_INF);
            if (vy && ((unsigned)gz < 64u)) v = *(const float4*)(src + (gz << 12));
            *(float4*)(S + z * PL + yy * 64 + x0) = v;
        }
    }
    __syncthreads();

    int lbase = yy * 64 + x0;
    int goff  = gy * 64 + x0;

    // ROWY: vertical 3-row max (float4) + horizontal 3-window via shuffles
    #define ROWY(zz_, Q, C) {                                                  \
        const float* pz = S + (zz_) * PL + lbase;                              \
        float4 r0 = *(const float4*)(pz - 64);                                 \
        float4 r1 = *(const float4*)(pz);                                      \
        float4 r2 = *(const float4*)(pz + 64);                                 \
        float4 cm;                                                             \
        cm.x = fmaxf(fmaxf(r0.x, r1.x), r2.x);                                 \
        cm.y = fmaxf(fmaxf(r0.y, r1.y), r2.y);                                 \
        cm.z = fmaxf(fmaxf(r0.z, r1.z), r2.z);                                 \
        cm.w = fmaxf(fmaxf(r0.w, r1.w), r2.w);                                 \
        float lm = __shfl(cm.w, lane - 1);                                     \
        float rm = __shfl(cm.x, lane + 1);                                     \
        if (x4 == 0)  lm = NEG_INF;                                            \
        if (x4 == 15) rm = NEG_INF;                                            \
        Q.x = fmaxf(lm, fmaxf(cm.x, cm.y));                                    \
        Q.y = fmaxf(cm.x, fmaxf(cm.y, cm.z));                                  \
        Q.z = fmaxf(cm.y, fmaxf(cm.z, cm.w));                                  \
        Q.w = fmaxf(fmaxf(cm.z, cm.w), rm);                                    \
        C = r1;                                                                \
    }

    #pragma unroll
    for (int it = 0; it < T; ++it) {
        const int lo   = 5 - T + it;
        const int span = ZMID - lo;          // compile-time; same for both halves
        bool act = (yy >= lo) && (yy < YC - lo);
        int zlo = h ? ZMID : lo;
        float4 vn[5];
        if (act) {
            float4 q0, q1, q2, c1, c2, cd;
            ROWY(zlo - 1, q0, cd);
            ROWY(zlo,     q1, c1);
            #pragma unroll
            for (int zi = 0; zi < span; ++zi) {
                int z = zlo + zi;
                ROWY(z + 1, q2, c2);
                int gz = tz + z - 4;
                float4 r;
                if (vy && ((unsigned)gz < 64u)) {
                    int off = (gz << 12) + goff;
                    float4 pv = *(const float4*)(pb + off);
                    float4 rv = *(const float4*)(rb + off);
                    float4 m3;
                    m3.x = fmaxf(fmaxf(q0.x, q1.x), q2.x);
                    m3.y = fmaxf(fmaxf(q0.y, q1.y), q2.y);
                    m3.z = fmaxf(fmaxf(q0.z, q1.z), q2.z);
                    m3.w = fmaxf(fmaxf(q0.w, q1.w), q2.w);
                    r.x = fmaxf(c1.x, fmaf(pv.x, m3.x - rv.x, rv.x));
                    r.y = fmaxf(c1.y, fmaf(pv.y, m3.y - rv.y, rv.y));
                    r.z = fmaxf(c1.z, fmaf(pv.z, m3.z - rv.z, rv.z));
                    r.w = fmaxf(c1.w, fmaf(pv.w, m3.w - rv.w, rv.w));
                    if (it == T - 1) *(float4*)(ob + off) = r;
                } else {
                    r = c1;    // out-of-volume stays -inf / stale
                }
                vn[zi] = r;
                q0 = q1; q1 = q2; c1 = c2;
            }
        }
        __syncthreads();
        if (act) {
            #pragma unroll
            for (int zi = 0; zi < span; ++zi)
                *(float4*)(S + (zlo + zi) * PL + lbase) = vn[zi];
        }
        __syncthreads();
    }
    #undef ROWY
}

extern "C" void kernel_launch(void* const* d_in, const int* in_sizes, int n_in,
                              void* d_out, int out_size, void* d_ws, size_t ws_size,
                              hipStream_t stream) {
    const float* img = (const float*)d_in[0];   // (4,2,64,64,64)
    const float* hw  = (const float*)d_in[1];   // (150,27)
    const float* hb  = (const float*)d_in[2];   // (150,)
    const float* pw  = (const float*)d_in[3];   // (150,)
    // d_in[4] = k (device scalar); reference fixes k=30.

    float* out = (float*)d_out;                      // X buffer (4 MB)
    float* p   = (float*)d_ws;                       // 4 MB
    float* vA  = (float*)((char*)d_ws + (4u << 20)); // Y buffer (4 MB)
    // padded bf16 volume (2.3 MB) shares the vA slot: used only before prop #1
    unsigned short* pad = (unsigned short*)((char*)d_ws + (4u << 20));

    pad_kernel<<<dim3(1124, 4), 256, 0, stream>>>(img, pad);
    gate_mfma<<<1024, 256, 0, stream>>>(pad, hw, hb, pw, p);

    const float* r0 = img + (1 << 18);  // r channel base, sample stride 2^19

    // 7*T4 + 1*T2 = 30 iterations; ping-pong ends in d_out.
    prop_kernel<4><<<512, 512, 0, stream>>>(r0,  1 << 19, r0, p, vA);   // img -> Y
    prop_kernel<4><<<512, 512, 0, stream>>>(vA,  1 << 18, r0, p, out);  // Y -> X
    prop_kernel<4><<<512, 512, 0, stream>>>(out, 1 << 18, r0, p, vA);
    prop_kernel<4><<<512, 512, 0, stream>>>(vA,  1 << 18, r0, p, out);
    prop_kernel<4><<<512, 512, 0, stream>>>(out, 1 << 18, r0, p, vA);
    prop_kernel<4><<<512, 512, 0, stream>>>(vA,  1 << 18, r0, p, out);
    prop_kernel<4><<<512, 512, 0, stream>>>(out, 1 << 18, r0, p, vA);
    prop_kernel<2><<<512, 512, 0, stream>>>(vA,  1 << 18, r0, p, out);  // -> d_out
}

// Round 3
// 204.777 us; speedup vs baseline: 1.1259x; 1.0723x over previous
//
#include <hip/hip_runtime.h>
#include <math.h>

#define NEG_INF (-__builtin_inff())

typedef __attribute__((ext_vector_type(8))) short short8;
typedef __attribute__((ext_vector_type(4))) float f32x4;

__device__ __forceinline__ unsigned f2bf(float f) {   // fp32 -> bf16 bits (RNE)
    union { float f; unsigned u; } v; v.f = f;
    return (v.u + 0x7fffu + ((v.u >> 16) & 1u)) >> 16;
}

// DPP row shifts within 16-lane rows (our x-rows are exactly 16 lanes).
// row_shr:1 (0x111): lane i reads lane i-1. row_shl:1 (0x101): lane i reads
// lane i+1. Out-of-row lanes get 0 (bound_ctrl) and are overridden by the
// existing x-edge NEG_INF cndmask. VALU op: no DS pipe, no lgkm wait.
__device__ __forceinline__ float dpp_shr1(float x) {
    return __int_as_float(__builtin_amdgcn_update_dpp(
        0, __float_as_int(x), 0x111, 0xF, 0xF, true));
}
__device__ __forceinline__ float dpp_shl1(float x) {
    return __int_as_float(__builtin_amdgcn_update_dpp(
        0, __float_as_int(x), 0x101, 0xF, 0xF, true));
}

// ============ pad kernel: x channel -> zero-padded (4,66,66,66) bf16 ============
// Padded cell (z,y,x) = volume voxel (z-1,y-1,x-1); pad ring = 0 (conv SAME).
__global__ __launch_bounds__(256) void pad_kernel(
    const float* __restrict__ img, unsigned short* __restrict__ pad)
{
    int i = blockIdx.x * 256 + threadIdx.x;      // cell within one sample
    if (i >= 66 * 66 * 66) return;
    int b = blockIdx.y;
    int z = i / 4356;
    int rem = i - z * 4356;
    int y = rem / 66;
    int x = rem - y * 66;
    float v = 0.f;
    if (z >= 1 && z <= 64 && y >= 1 && y <= 64 && x >= 1 && x <= 64)
        v = img[((size_t)b << 19) + ((z - 1) << 12) + ((y - 1) << 6) + (x - 1)];
    pad[(size_t)b * 287496 + i] = (unsigned short)f2bf(v);
}

// ============ gate via MFMA: p = sigmoid(sum_c pw[c]*relu(conv(x)+hb[c])) ======
// (Round-0 version restored verbatim: swapped-operand round-2 variant caused a
// 4x HBM-traffic regression.)
// GEMM: A[m=voxel][k=tap] * B[k][n=channel]; K=27 taps + bias row (k=27, A=1.0,
// B=hb) padded to 32; N=150 padded to 160 (10 tiles). 16x16x32 bf16 MFMA.
// A frag: lane holds A[m=lane&15][k=(lane>>4)*8+j]; B: B[k=(lane>>4)*8+j][n=lane&15];
// D: col=lane&15, row=(lane>>4)*4+reg.
__global__ __launch_bounds__(256, 2) void gate_mfma(
    const unsigned short* __restrict__ pad,
    const float* __restrict__ hw, const float* __restrict__ hb,
    const float* __restrict__ pw, float* __restrict__ p)
{
    const int lane = threadIdx.x & 63;
    const int col  = lane & 15;          // B: channel-in-tile; A: voxel m
    const int q    = lane >> 4;
    const int W    = blockIdx.x * 4 + (threadIdx.x >> 6);   // 4096 waves

    // ---- B fragments + pw, built once per wave
    int4  bfrag[10];
    float pwv[10];
    #pragma unroll
    for (int t = 0; t < 10; ++t) {
        int c = 16 * t + col;
        bool cv = c < 150;
        unsigned hv[8];
        #pragma unroll
        for (int j = 0; j < 8; ++j) {
            int k = 8 * q + j;
            float wv = 0.f;
            if (cv) {
                if (k < 27) wv = hw[c * 27 + k];
                else if (k == 27) wv = hb[c];
            }
            hv[j] = f2bf(wv);
        }
        bfrag[t] = make_int4(hv[0] | (hv[1] << 16), hv[2] | (hv[3] << 16),
                             hv[4] | (hv[5] << 16), hv[6] | (hv[7] << 16));
        pwv[t] = cv ? pw[c] : 0.f;
    }

    // ---- per-lane A-tap offsets into padded volume (loop-invariant)
    int offL[8]; unsigned cstA[8]; bool ldA[8];
    #pragma unroll
    for (int j = 0; j < 8; ++j) {
        int k = 8 * q + j;
        int dz = (k * 57) >> 9;          // k/9 for k<32
        int rem = k - 9 * dz;
        int dy = (rem * 171) >> 9;       // rem/3
        int dx = rem - 3 * dy;
        ldA[j]  = (k < 27);
        offL[j] = (k < 27) ? (dz * 4356 + dy * 66 + dx) : 0;
        cstA[j] = (k == 27) ? 0x3F80u : 0u;   // bias row: bf16(1.0)
    }

    // ---- 16 groups of 16 voxels per wave
    for (int i = 0; i < 16; ++i) {
        int g   = W * 16 + i;
        int x0  = (g & 3) << 4;
        int row = g >> 2;
        int y = row & 63, zz = (row >> 6) & 63, b = row >> 12;
        int abase = b * 287496 + zz * 4356 + y * 66 + x0 + col;

        unsigned av[8];
        #pragma unroll
        for (int j = 0; j < 8; ++j) {
            unsigned v = pad[abase + offL[j]];
            av[j] = ldA[j] ? v : cstA[j];
        }
        union { int4 i4; short8 s8; } af, bfu;
        af.i4 = make_int4(av[0] | (av[1] << 16), av[2] | (av[3] << 16),
                          av[4] | (av[5] << 16), av[6] | (av[7] << 16));

        const f32x4 zero = {0.f, 0.f, 0.f, 0.f};
        f32x4 rr[10];
        #pragma unroll
        for (int t = 0; t < 10; ++t) {
            bfu.i4 = bfrag[t];
            rr[t] = __builtin_amdgcn_mfma_f32_16x16x32_bf16(af.s8, bfu.s8, zero, 0, 0, 0);
        }
        float ax = 0.f, ay = 0.f, az = 0.f, aw = 0.f;
        #pragma unroll
        for (int t = 0; t < 10; ++t) {
            ax = fmaf(pwv[t], fmaxf(rr[t].x, 0.f), ax);
            ay = fmaf(pwv[t], fmaxf(rr[t].y, 0.f), ay);
            az = fmaf(pwv[t], fmaxf(rr[t].z, 0.f), az);
            aw = fmaf(pwv[t], fmaxf(rr[t].w, 0.f), aw);
        }
        #pragma unroll
        for (int m = 1; m < 16; m <<= 1) {
            ax += __shfl_xor(ax, m);
            ay += __shfl_xor(ay, m);
            az += __shfl_xor(az, m);
            aw += __shfl_xor(aw, m);
        }
        if (col == 0) {                  // rows 4q..4q+3 = x0+4q..x0+4q+3
            float4 o;
            o.x = 1.f / (1.f + __expf(-ax));
            o.y = 1.f / (1.f + __expf(-ay));
            o.z = 1.f / (1.f + __expf(-az));
            o.w = 1.f / (1.f + __expf(-aw));
            *(float4*)(p + (b << 18) + (zz << 12) + (y << 6) + x0 + 4 * q) = o;
        }
    }
}

// ============ fused propagation: in-place 48 KB LDS cube, compile-time T ======
// Cube 12z x 16y x 64x; output tile 4z x 8y x 64x (margins 4). Iteration it
// (lo=5-T+it) updates z,y in [lo, dim-lo); shrinking validity keeps it exact.
// 512 threads/block — bit 8 picks a z-half: h0 handles [lo,6), h1 [6,12-lo).
// ZC=12/mid=6 keeps the halves perfectly balanced (spans 5/5,4/4,3/3,2/2).
// 2 blocks/CU = 16 waves/CU = 4 waves/SIMD.
// x-edge maxima via DPP row-shifts (VALU) instead of ds_bpermute shuffles:
// removes 44 DS-pipe ops + their lgkm chains per thread per launch.
#define ZC 12
#define YC 16
#define PL 1024   // 16*64 floats per z-plane
#define ZMID 6

template<int T>
__global__ __launch_bounds__(512, 4) void prop_kernel(
    const float* __restrict__ vin, int sstride,
    const float* __restrict__ rimg,   // r base = img + 2^18, sample stride 2^19
    const float* __restrict__ pbuf,   // p, sample stride 2^18
    float* __restrict__ vout)
{
    __shared__ float S[ZC * PL];
    int blk = blockIdx.x;             // 512 blocks: b(4) x tz(16) x ty(8)
    int b  = blk >> 7;
    int tz = ((blk >> 3) & 15) << 2;
    int ty = (blk & 7) << 3;

    const float* vb = vin  + (size_t)b * sstride;
    const float* rb = rimg + ((size_t)b << 19);
    const float* pb = pbuf + ((size_t)b << 18);
    float*       ob = vout + ((size_t)b << 18);

    int tid  = threadIdx.x;
    int x4   = tid & 15, x0 = x4 << 2;
    int yy   = (tid >> 4) & 15;
    int h    = tid >> 8;              // z-half
    int lane = tid & 63;
    (void)lane;

    int gy = ty + yy - 4;
    bool vy = (unsigned)gy < 64u;

    // ---- stage: half h stages planes [6h, 6h+6)
    {
        const float* src = vb + gy * 64 + x0;
        #pragma unroll
        for (int zi = 0; zi < 6; ++zi) {
            int z  = 6 * h + zi;
            int gz = tz + z - 4;
            float4 v = make_float4(NEG_INF, NEG_INF, NEG_INF, NEG_INF);
            if (vy && ((unsigned)gz < 64u)) v = *(const float4*)(src + (gz << 12));
            *(float4*)(S + z * PL + yy * 64 + x0) = v;
        }
    }
    __syncthreads();

    int lbase = yy * 64 + x0;
    int goff  = gy * 64 + x0;

    // ROWY: vertical 3-row max (float4) + horizontal 3-window via DPP shifts
    #define ROWY(zz_, Q, C) {                                                  \
        const float* pz = S + (zz_) * PL + lbase;                              \
        float4 r0 = *(const float4*)(pz - 64);                                 \
        float4 r1 = *(const float4*)(pz);                                      \
        float4 r2 = *(const float4*)(pz + 64);                                 \
        float4 cm;                                                             \
        cm.x = fmaxf(fmaxf(r0.x, r1.x), r2.x);                                 \
        cm.y = fmaxf(fmaxf(r0.y, r1.y), r2.y);                                 \
        cm.z = fmaxf(fmaxf(r0.z, r1.z), r2.z);                                 \
        cm.w = fmaxf(fmaxf(r0.w, r1.w), r2.w);                                 \
        float lm = dpp_shr1(cm.w);       /* lane i-1's cm.w */                 \
        float rm = dpp_shl1(cm.x);       /* lane i+1's cm.x */                 \
        if (x4 == 0)  lm = NEG_INF;                                            \
        if (x4 == 15) rm = NEG_INF;                                            \
        Q.x = fmaxf(lm, fmaxf(cm.x, cm.y));                                    \
        Q.y = fmaxf(cm.x, fmaxf(cm.y, cm.z));                                  \
        Q.z = fmaxf(cm.y, fmaxf(cm.z, cm.w));                                  \
        Q.w = fmaxf(fmaxf(cm.z, cm.w), rm);                                    \
        C = r1;                                                                \
    }

    #pragma unroll
    for (int it = 0; it < T; ++it) {
        const int lo   = 5 - T + it;
        const int span = ZMID - lo;          // compile-time; same for both halves
        bool act = (yy >= lo) && (yy < YC - lo);
        int zlo = h ? ZMID : lo;
        float4 vn[5];
        if (act) {
            float4 q0, q1, q2, c1, c2, cd;
            ROWY(zlo - 1, q0, cd);
            ROWY(zlo,     q1, c1);
            #pragma unroll
            for (int zi = 0; zi < span; ++zi) {
                int z = zlo + zi;
                ROWY(z + 1, q2, c2);
                int gz = tz + z - 4;
                float4 r;
                if (vy && ((unsigned)gz < 64u)) {
                    int off = (gz << 12) + goff;
                    float4 pv = *(const float4*)(pb + off);
                    float4 rv = *(const float4*)(rb + off);
                    float4 m3;
                    m3.x = fmaxf(fmaxf(q0.x, q1.x), q2.x);
                    m3.y = fmaxf(fmaxf(q0.y, q1.y), q2.y);
                    m3.z = fmaxf(fmaxf(q0.z, q1.z), q2.z);
                    m3.w = fmaxf(fmaxf(q0.w, q1.w), q2.w);
                    r.x = fmaxf(c1.x, fmaf(pv.x, m3.x - rv.x, rv.x));
                    r.y = fmaxf(c1.y, fmaf(pv.y, m3.y - rv.y, rv.y));
                    r.z = fmaxf(c1.z, fmaf(pv.z, m3.z - rv.z, rv.z));
                    r.w = fmaxf(c1.w, fmaf(pv.w, m3.w - rv.w, rv.w));
                    if (it == T - 1) *(float4*)(ob + off) = r;
                } else {
                    r = c1;    // out-of-volume stays -inf / stale
                }
                vn[zi] = r;
                q0 = q1; q1 = q2; c1 = c2;
            }
        }
        __syncthreads();
        if (act) {
            #pragma unroll
            for (int zi = 0; zi < span; ++zi)
                *(float4*)(S + (zlo + zi) * PL + lbase) = vn[zi];
        }
        __syncthreads();
    }
    #undef ROWY
}

extern "C" void kernel_launch(void* const* d_in, const int* in_sizes, int n_in,
                              void* d_out, int out_size, void* d_ws, size_t ws_size,
                              hipStream_t stream) {
    const float* img = (const float*)d_in[0];   // (4,2,64,64,64)
    const float* hw  = (const float*)d_in[1];   // (150,27)
    const float* hb  = (const float*)d_in[2];   // (150,)
    const float* pw  = (const float*)d_in[3];   // (150,)
    // d_in[4] = k (device scalar); reference fixes k=30.

    float* out = (float*)d_out;                      // X buffer (4 MB)
    float* p   = (float*)d_ws;                       // 4 MB
    float* vA  = (float*)((char*)d_ws + (4u << 20)); // Y buffer (4 MB)
    // padded bf16 volume (2.3 MB) shares the vA slot: used only before prop #1
    unsigned short* pad = (unsigned short*)((char*)d_ws + (4u << 20));

    pad_kernel<<<dim3(1124, 4), 256, 0, stream>>>(img, pad);
    gate_mfma<<<1024, 256, 0, stream>>>(pad, hw, hb, pw, p);

    const float* r0 = img + (1 << 18);  // r channel base, sample stride 2^19

    // 7*T4 + 1*T2 = 30 iterations; ping-pong ends in d_out.
    prop_kernel<4><<<512, 512, 0, stream>>>(r0,  1 << 19, r0, p, vA);   // img -> Y
    prop_kernel<4><<<512, 512, 0, stream>>>(vA,  1 << 18, r0, p, out);  // Y -> X
    prop_kernel<4><<<512, 512, 0, stream>>>(out, 1 << 18, r0, p, vA);
    prop_kernel<4><<<512, 512, 0, stream>>>(vA,  1 << 18, r0, p, out);
    prop_kernel<4><<<512, 512, 0, stream>>>(out, 1 << 18, r0, p, vA);
    prop_kernel<4><<<512, 512, 0, stream>>>(vA,  1 << 18, r0, p, out);
    prop_kernel<4><<<512, 512, 0, stream>>>(out, 1 << 18, r0, p, vA);
    prop_kernel<2><<<512, 512, 0, stream>>>(vA,  1 << 18, r0, p, out);  // -> d_out
}

// Round 4
// 203.879 us; speedup vs baseline: 1.1309x; 1.0044x over previous
//
#include <hip/hip_runtime.h>
#include <math.h>

#define NEG_INF (-__builtin_inff())

typedef __attribute__((ext_vector_type(8))) short short8;
typedef __attribute__((ext_vector_type(4))) float f32x4;

__device__ __forceinline__ unsigned f2bf(float f) {   // fp32 -> bf16 bits (RNE)
    union { float f; unsigned u; } v; v.f = f;
    return (v.u + 0x7fffu + ((v.u >> 16) & 1u)) >> 16;
}

// DPP row shifts within 16-lane rows. row_shr:n (0x110|n): lane i reads lane
// i-n within its 16-lane row; bound_ctrl=true -> out-of-row reads 0.
// VALU op: no DS pipe, no lgkm wait.
__device__ __forceinline__ float dpp_shr1(float x) {
    return __int_as_float(__builtin_amdgcn_update_dpp(
        0, __float_as_int(x), 0x111, 0xF, 0xF, true));
}
__device__ __forceinline__ float dpp_shr2(float x) {
    return __int_as_float(__builtin_amdgcn_update_dpp(
        0, __float_as_int(x), 0x112, 0xF, 0xF, true));
}
__device__ __forceinline__ float dpp_shr4(float x) {
    return __int_as_float(__builtin_amdgcn_update_dpp(
        0, __float_as_int(x), 0x114, 0xF, 0xF, true));
}
__device__ __forceinline__ float dpp_shr8(float x) {
    return __int_as_float(__builtin_amdgcn_update_dpp(
        0, __float_as_int(x), 0x118, 0xF, 0xF, true));
}
__device__ __forceinline__ float dpp_shl1(float x) {
    return __int_as_float(__builtin_amdgcn_update_dpp(
        0, __float_as_int(x), 0x101, 0xF, 0xF, true));
}

// ============ pad kernel: x channel -> zero-padded (4,66,66,66) bf16 ============
// Padded cell (z,y,x) = volume voxel (z-1,y-1,x-1); pad ring = 0 (conv SAME).
__global__ __launch_bounds__(256) void pad_kernel(
    const float* __restrict__ img, unsigned short* __restrict__ pad)
{
    int i = blockIdx.x * 256 + threadIdx.x;      // cell within one sample
    if (i >= 66 * 66 * 66) return;
    int b = blockIdx.y;
    int z = i / 4356;
    int rem = i - z * 4356;
    int y = rem / 66;
    int x = rem - y * 66;
    float v = 0.f;
    if (z >= 1 && z <= 64 && y >= 1 && y <= 64 && x >= 1 && x <= 64)
        v = img[((size_t)b << 19) + ((z - 1) << 12) + ((y - 1) << 6) + (x - 1)];
    pad[(size_t)b * 287496 + i] = (unsigned short)f2bf(v);
}

// ============ gate via MFMA: p = sigmoid(sum_c pw[c]*relu(conv(x)+hb[c])) ======
// GEMM: A[m=voxel][k=tap] * B[k][n=channel]; K=27 taps + bias row (k=27, A=1.0,
// B=hb) padded to 32; N=150 padded to 160 (10 tiles). 16x16x32 bf16 MFMA.
// A frag: lane holds A[m=lane&15][k=(lane>>4)*8+j]; B: B[k=(lane>>4)*8+j][n=lane&15];
// D: col=lane&15, row=(lane>>4)*4+reg.
// v3: B fragments are lane-indexed only (same for every wave) -> built once per
// BLOCK (waves split the 10 tiles), staged via 10 KB LDS. Cheap prologue lets
// grid go 1024->4096 (4 groups/wave): 8 blocks/CU = 32 waves/CU = 8 waves/SIMD
// at VGPR<=64. Channel reduce via DPP row_shr scan (no DS ops), store col 15.
__global__ __launch_bounds__(256, 4) void gate_mfma(
    const unsigned short* __restrict__ pad,
    const float* __restrict__ hw, const float* __restrict__ hb,
    const float* __restrict__ pw, float* __restrict__ p)
{
    __shared__ int4 Bsh[10 * 64];        // [t][lane] 16B fragments

    const int lane = threadIdx.x & 63;
    const int col  = lane & 15;          // B: channel-in-tile; A: voxel m
    const int q    = lane >> 4;
    const int wid  = threadIdx.x >> 6;
    const int W    = blockIdx.x * 4 + wid;   // 16384 waves; row = W

    // ---- build B tiles cooperatively: wave w builds t = w, w+4, w+8
    for (int t = wid; t < 10; t += 4) {
        int c = 16 * t + col;
        bool cv = c < 150;
        unsigned hv[8];
        #pragma unroll
        for (int j = 0; j < 8; ++j) {
            int k = 8 * q + j;
            float wv = 0.f;
            if (cv) {
                if (k < 27) wv = hw[c * 27 + k];
                else if (k == 27) wv = hb[c];
            }
            hv[j] = f2bf(wv);
        }
        Bsh[t * 64 + lane] = make_int4(hv[0] | (hv[1] << 16), hv[2] | (hv[3] << 16),
                                       hv[4] | (hv[5] << 16), hv[6] | (hv[7] << 16));
    }
    // ---- pw per lane (L1-resident after first wave)
    float pwv[10];
    #pragma unroll
    for (int t = 0; t < 10; ++t) {
        int c = 16 * t + col;
        pwv[t] = (c < 150) ? pw[c] : 0.f;
    }
    __syncthreads();

    int4 bfrag[10];
    #pragma unroll
    for (int t = 0; t < 10; ++t) bfrag[t] = Bsh[t * 64 + lane];

    // ---- per-lane A-tap offsets into padded volume (loop-invariant)
    int offL[8]; unsigned cstA[8]; bool ldA[8];
    #pragma unroll
    for (int j = 0; j < 8; ++j) {
        int k = 8 * q + j;
        int dz = (k * 57) >> 9;          // k/9 for k<32
        int rem = k - 9 * dz;
        int dy = (rem * 171) >> 9;       // rem/3
        int dx = rem - 3 * dy;
        ldA[j]  = (k < 27);
        offL[j] = (k < 27) ? (dz * 4356 + dy * 66 + dx) : 0;
        cstA[j] = (k == 27) ? 0x3F80u : 0u;   // bias row: bf16(1.0)
    }

    // ---- 4 groups of 16 voxels per wave: one full x-row (y=W&63)
    int y = W & 63, zz = (W >> 6) & 63, b = W >> 12;
    int rbase = b * 287496 + zz * 4356 + y * 66 + col;

    #pragma unroll 2
    for (int i = 0; i < 4; ++i) {
        int x0    = i << 4;
        int abase = rbase + x0;

        unsigned av[8];
        #pragma unroll
        for (int j = 0; j < 8; ++j) {
            unsigned v = pad[abase + offL[j]];
            av[j] = ldA[j] ? v : cstA[j];
        }
        union { int4 i4; short8 s8; } af, bfu;
        af.i4 = make_int4(av[0] | (av[1] << 16), av[2] | (av[3] << 16),
                          av[4] | (av[5] << 16), av[6] | (av[7] << 16));

        const f32x4 zero = {0.f, 0.f, 0.f, 0.f};
        f32x4 rr[10];
        #pragma unroll
        for (int t = 0; t < 10; ++t) {
            bfu.i4 = bfrag[t];
            rr[t] = __builtin_amdgcn_mfma_f32_16x16x32_bf16(af.s8, bfu.s8, zero, 0, 0, 0);
        }
        float ax = 0.f, ay = 0.f, az = 0.f, aw = 0.f;
        #pragma unroll
        for (int t = 0; t < 10; ++t) {
            ax = fmaf(pwv[t], fmaxf(rr[t].x, 0.f), ax);
            ay = fmaf(pwv[t], fmaxf(rr[t].y, 0.f), ay);
            az = fmaf(pwv[t], fmaxf(rr[t].z, 0.f), az);
            aw = fmaf(pwv[t], fmaxf(rr[t].w, 0.f), aw);
        }
        // sum across the 16 cols: DPP prefix-scan (shr 1,2,4,8); col 15 = total
        ax += dpp_shr1(ax); ax += dpp_shr2(ax); ax += dpp_shr4(ax); ax += dpp_shr8(ax);
        ay += dpp_shr1(ay); ay += dpp_shr2(ay); ay += dpp_shr4(ay); ay += dpp_shr8(ay);
        az += dpp_shr1(az); az += dpp_shr2(az); az += dpp_shr4(az); az += dpp_shr8(az);
        aw += dpp_shr1(aw); aw += dpp_shr2(aw); aw += dpp_shr4(aw); aw += dpp_shr8(aw);
        if (col == 15) {                 // rows 4q..4q+3 = x0+4q..x0+4q+3
            float4 o;
            o.x = 1.f / (1.f + __expf(-ax));
            o.y = 1.f / (1.f + __expf(-ay));
            o.z = 1.f / (1.f + __expf(-az));
            o.w = 1.f / (1.f + __expf(-aw));
            *(float4*)(p + (b << 18) + (zz << 12) + (y << 6) + x0 + 4 * q) = o;
        }
    }
}

// ============ fused propagation: in-place 48 KB LDS cube, compile-time T ======
// (unchanged from round 3 for a clean gate A/B)
#define ZC 12
#define YC 16
#define PL 1024   // 16*64 floats per z-plane
#define ZMID 6

template<int T>
__global__ __launch_bounds__(512, 4) void prop_kernel(
    const float* __restrict__ vin, int sstride,
    const float* __restrict__ rimg,   // r base = img + 2^18, sample stride 2^19
    const float* __restrict__ pbuf,   // p, sample stride 2^18
    float* __restrict__ vout)
{
    __shared__ float S[ZC * PL];
    int blk = blockIdx.x;             // 512 blocks: b(4) x tz(16) x ty(8)
    int b  = blk >> 7;
    int tz = ((blk >> 3) & 15) << 2;
    int ty = (blk & 7) << 3;

    const float* vb = vin  + (size_t)b * sstride;
    const float* rb = rimg + ((size_t)b << 19);
    const float* pb = pbuf + ((size_t)b << 18);
    float*       ob = vout + ((size_t)b << 18);

    int tid  = threadIdx.x;
    int x4   = tid & 15, x0 = x4 << 2;
    int yy   = (tid >> 4) & 15;
    int h    = tid >> 8;              // z-half
    int lane = tid & 63;
    (void)lane;

    int gy = ty + yy - 4;
    bool vy = (unsigned)gy < 64u;

    // ---- stage: half h stages planes [6h, 6h+6)
    {
        const float* src = vb + gy * 64 + x0;
        #pragma unroll
        for (int zi = 0; zi < 6; ++zi) {
            int z  = 6 * h + zi;
            int gz = tz + z - 4;
            float4 v = make_float4(NEG_INF, NEG_INF, NEG_INF, NEG_INF);
            if (vy && ((unsigned)gz < 64u)) v = *(const float4*)(src + (gz << 12));
            *(float4*)(S + z * PL + yy * 64 + x0) = v;
        }
    }
    __syncthreads();

    int lbase = yy * 64 + x0;
    int goff  = gy * 64 + x0;

    // ROWY: vertical 3-row max (float4) + horizontal 3-window via DPP shifts
    #define ROWY(zz_, Q, C) {                                                  \
        const float* pz = S + (zz_) * PL + lbase;                              \
        float4 r0 = *(const float4*)(pz - 64);                                 \
        float4 r1 = *(const float4*)(pz);                                      \
        float4 r2 = *(const float4*)(pz + 64);                                 \
        float4 cm;                                                             \
        cm.x = fmaxf(fmaxf(r0.x, r1.x), r2.x);                                 \
        cm.y = fmaxf(fmaxf(r0.y, r1.y), r2.y);                                 \
        cm.z = fmaxf(fmaxf(r0.z, r1.z), r2.z);                                 \
        cm.w = fmaxf(fmaxf(r0.w, r1.w), r2.w);                                 \
        float lm = dpp_shr1(cm.w);       /* lane i-1's cm.w */                 \
        float rm = dpp_shl1(cm.x);       /* lane i+1's cm.x */                 \
        if (x4 == 0)  lm = NEG_INF;                                            \
        if (x4 == 15) rm = NEG_INF;                                            \
        Q.x = fmaxf(lm, fmaxf(cm.x, cm.y));                                    \
        Q.y = fmaxf(cm.x, fmaxf(cm.y, cm.z));                                  \
        Q.z = fmaxf(cm.y, fmaxf(cm.z, cm.w));                                  \
        Q.w = fmaxf(fmaxf(cm.z, cm.w), rm);                                    \
        C = r1;                                                                \
    }

    #pragma unroll
    for (int it = 0; it < T; ++it) {
        const int lo   = 5 - T + it;
        const int span = ZMID - lo;          // compile-time; same for both halves
        bool act = (yy >= lo) && (yy < YC - lo);
        int zlo = h ? ZMID : lo;
        float4 vn[5];
        if (act) {
            float4 q0, q1, q2, c1, c2, cd;
            ROWY(zlo - 1, q0, cd);
            ROWY(zlo,     q1, c1);
            #pragma unroll
            for (int zi = 0; zi < span; ++zi) {
                int z = zlo + zi;
                ROWY(z + 1, q2, c2);
                int gz = tz + z - 4;
                float4 r;
                if (vy && ((unsigned)gz < 64u)) {
                    int off = (gz << 12) + goff;
                    float4 pv = *(const float4*)(pb + off);
                    float4 rv = *(const float4*)(rb + off);
                    float4 m3;
                    m3.x = fmaxf(fmaxf(q0.x, q1.x), q2.x);
                    m3.y = fmaxf(fmaxf(q0.y, q1.y), q2.y);
                    m3.z = fmaxf(fmaxf(q0.z, q1.z), q2.z);
                    m3.w = fmaxf(fmaxf(q0.w, q1.w), q2.w);
                    r.x = fmaxf(c1.x, fmaf(pv.x, m3.x - rv.x, rv.x));
                    r.y = fmaxf(c1.y, fmaf(pv.y, m3.y - rv.y, rv.y));
                    r.z = fmaxf(c1.z, fmaf(pv.z, m3.z - rv.z, rv.z));
                    r.w = fmaxf(c1.w, fmaf(pv.w, m3.w - rv.w, rv.w));
                    if (it == T - 1) *(float4*)(ob + off) = r;
                } else {
                    r = c1;    // out-of-volume stays -inf / stale
                }
                vn[zi] = r;
                q0 = q1; q1 = q2; c1 = c2;
            }
        }
        __syncthreads();
        if (act) {
            #pragma unroll
            for (int zi = 0; zi < span; ++zi)
                *(float4*)(S + (zlo + zi) * PL + lbase) = vn[zi];
        }
        __syncthreads();
    }
    #undef ROWY
}

extern "C" void kernel_launch(void* const* d_in, const int* in_sizes, int n_in,
                              void* d_out, int out_size, void* d_ws, size_t ws_size,
                              hipStream_t stream) {
    const float* img = (const float*)d_in[0];   // (4,2,64,64,64)
    const float* hw  = (const float*)d_in[1];   // (150,27)
    const float* hb  = (const float*)d_in[2];   // (150,)
    const float* pw  = (const float*)d_in[3];   // (150,)
    // d_in[4] = k (device scalar); reference fixes k=30.

    float* out = (float*)d_out;                      // X buffer (4 MB)
    float* p   = (float*)d_ws;                       // 4 MB
    float* vA  = (float*)((char*)d_ws + (4u << 20)); // Y buffer (4 MB)
    // padded bf16 volume (2.3 MB) shares the vA slot: used only before prop #1
    unsigned short* pad = (unsigned short*)((char*)d_ws + (4u << 20));

    pad_kernel<<<dim3(1124, 4), 256, 0, stream>>>(img, pad);
    gate_mfma<<<4096, 256, 0, stream>>>(pad, hw, hb, pw, p);

    const float* r0 = img + (1 << 18);  // r channel base, sample stride 2^19

    // 7*T4 + 1*T2 = 30 iterations; ping-pong ends in d_out.
    prop_kernel<4><<<512, 512, 0, stream>>>(r0,  1 << 19, r0, p, vA);   // img -> Y
    prop_kernel<4><<<512, 512, 0, stream>>>(vA,  1 << 18, r0, p, out);  // Y -> X
    prop_kernel<4><<<512, 512, 0, stream>>>(out, 1 << 18, r0, p, vA);
    prop_kernel<4><<<512, 512, 0, stream>>>(vA,  1 << 18, r0, p, out);
    prop_kernel<4><<<512, 512, 0, stream>>>(out, 1 << 18, r0, p, vA);
    prop_kernel<4><<<512, 512, 0, stream>>>(vA,  1 << 18, r0, p, out);
    prop_kernel<4><<<512, 512, 0, stream>>>(out, 1 << 18, r0, p, vA);
    prop_kernel<2><<<512, 512, 0, stream>>>(vA,  1 << 18, r0, p, out);  // -> d_out
}

// Round 5
// 203.204 us; speedup vs baseline: 1.1347x; 1.0033x over previous
//
#include <hip/hip_runtime.h>
#include <math.h>

#define NEG_INF (-__builtin_inff())

typedef __attribute__((ext_vector_type(8))) short short8;
typedef __attribute__((ext_vector_type(4))) float f32x4;

__device__ __forceinline__ unsigned f2bf(float f) {   // fp32 -> bf16 bits (RNE)
    union { float f; unsigned u; } v; v.f = f;
    return (v.u + 0x7fffu + ((v.u >> 16) & 1u)) >> 16;
}

// DPP row shifts within 16-lane rows. row_shr:n (0x110|n): lane i reads lane
// i-n within its 16-lane row; bound_ctrl=true -> out-of-row reads 0.
// VALU op: no DS pipe, no lgkm wait.
__device__ __forceinline__ float dpp_shr1(float x) {
    return __int_as_float(__builtin_amdgcn_update_dpp(
        0, __float_as_int(x), 0x111, 0xF, 0xF, true));
}
__device__ __forceinline__ float dpp_shr2(float x) {
    return __int_as_float(__builtin_amdgcn_update_dpp(
        0, __float_as_int(x), 0x112, 0xF, 0xF, true));
}
__device__ __forceinline__ float dpp_shr4(float x) {
    return __int_as_float(__builtin_amdgcn_update_dpp(
        0, __float_as_int(x), 0x114, 0xF, 0xF, true));
}
__device__ __forceinline__ float dpp_shr8(float x) {
    return __int_as_float(__builtin_amdgcn_update_dpp(
        0, __float_as_int(x), 0x118, 0xF, 0xF, true));
}
__device__ __forceinline__ float dpp_shl1(float x) {
    return __int_as_float(__builtin_amdgcn_update_dpp(
        0, __float_as_int(x), 0x101, 0xF, 0xF, true));
}

// ============ pad kernel: x channel -> zero-padded (4,66,66,66) bf16 ============
// Padded cell (z,y,x) = volume voxel (z-1,y-1,x-1); pad ring = 0 (conv SAME).
__global__ __launch_bounds__(256) void pad_kernel(
    const float* __restrict__ img, unsigned short* __restrict__ pad)
{
    int i = blockIdx.x * 256 + threadIdx.x;      // cell within one sample
    if (i >= 66 * 66 * 66) return;
    int b = blockIdx.y;
    int z = i / 4356;
    int rem = i - z * 4356;
    int y = rem / 66;
    int x = rem - y * 66;
    float v = 0.f;
    if (z >= 1 && z <= 64 && y >= 1 && y <= 64 && x >= 1 && x <= 64)
        v = img[((size_t)b << 19) + ((z - 1) << 12) + ((y - 1) << 6) + (x - 1)];
    pad[(size_t)b * 287496 + i] = (unsigned short)f2bf(v);
}

// ============ gate via MFMA (FROZEN from round 4 for clean prop A/B) ==========
__global__ __launch_bounds__(256, 4) void gate_mfma(
    const unsigned short* __restrict__ pad,
    const float* __restrict__ hw, const float* __restrict__ hb,
    const float* __restrict__ pw, float* __restrict__ p)
{
    __shared__ int4 Bsh[10 * 64];        // [t][lane] 16B fragments

    const int lane = threadIdx.x & 63;
    const int col  = lane & 15;          // B: channel-in-tile; A: voxel m
    const int q    = lane >> 4;
    const int wid  = threadIdx.x >> 6;
    const int W    = blockIdx.x * 4 + wid;   // 16384 waves; row = W

    // ---- build B tiles cooperatively: wave w builds t = w, w+4, w+8
    for (int t = wid; t < 10; t += 4) {
        int c = 16 * t + col;
        bool cv = c < 150;
        unsigned hv[8];
        #pragma unroll
        for (int j = 0; j < 8; ++j) {
            int k = 8 * q + j;
            float wv = 0.f;
            if (cv) {
                if (k < 27) wv = hw[c * 27 + k];
                else if (k == 27) wv = hb[c];
            }
            hv[j] = f2bf(wv);
        }
        Bsh[t * 64 + lane] = make_int4(hv[0] | (hv[1] << 16), hv[2] | (hv[3] << 16),
                                       hv[4] | (hv[5] << 16), hv[6] | (hv[7] << 16));
    }
    // ---- pw per lane (L1-resident after first wave)
    float pwv[10];
    #pragma unroll
    for (int t = 0; t < 10; ++t) {
        int c = 16 * t + col;
        pwv[t] = (c < 150) ? pw[c] : 0.f;
    }
    __syncthreads();

    int4 bfrag[10];
    #pragma unroll
    for (int t = 0; t < 10; ++t) bfrag[t] = Bsh[t * 64 + lane];

    // ---- per-lane A-tap offsets into padded volume (loop-invariant)
    int offL[8]; unsigned cstA[8]; bool ldA[8];
    #pragma unroll
    for (int j = 0; j < 8; ++j) {
        int k = 8 * q + j;
        int dz = (k * 57) >> 9;          // k/9 for k<32
        int rem = k - 9 * dz;
        int dy = (rem * 171) >> 9;       // rem/3
        int dx = rem - 3 * dy;
        ldA[j]  = (k < 27);
        offL[j] = (k < 27) ? (dz * 4356 + dy * 66 + dx) : 0;
        cstA[j] = (k == 27) ? 0x3F80u : 0u;   // bias row: bf16(1.0)
    }

    // ---- 4 groups of 16 voxels per wave: one full x-row (y=W&63)
    int y = W & 63, zz = (W >> 6) & 63, b = W >> 12;
    int rbase = b * 287496 + zz * 4356 + y * 66 + col;

    #pragma unroll 2
    for (int i = 0; i < 4; ++i) {
        int x0    = i << 4;
        int abase = rbase + x0;

        unsigned av[8];
        #pragma unroll
        for (int j = 0; j < 8; ++j) {
            unsigned v = pad[abase + offL[j]];
            av[j] = ldA[j] ? v : cstA[j];
        }
        union { int4 i4; short8 s8; } af, bfu;
        af.i4 = make_int4(av[0] | (av[1] << 16), av[2] | (av[3] << 16),
                          av[4] | (av[5] << 16), av[6] | (av[7] << 16));

        const f32x4 zero = {0.f, 0.f, 0.f, 0.f};
        f32x4 rr[10];
        #pragma unroll
        for (int t = 0; t < 10; ++t) {
            bfu.i4 = bfrag[t];
            rr[t] = __builtin_amdgcn_mfma_f32_16x16x32_bf16(af.s8, bfu.s8, zero, 0, 0, 0);
        }
        float ax = 0.f, ay = 0.f, az = 0.f, aw = 0.f;
        #pragma unroll
        for (int t = 0; t < 10; ++t) {
            ax = fmaf(pwv[t], fmaxf(rr[t].x, 0.f), ax);
            ay = fmaf(pwv[t], fmaxf(rr[t].y, 0.f), ay);
            az = fmaf(pwv[t], fmaxf(rr[t].z, 0.f), az);
            aw = fmaf(pwv[t], fmaxf(rr[t].w, 0.f), aw);
        }
        // sum across the 16 cols: DPP prefix-scan (shr 1,2,4,8); col 15 = total
        ax += dpp_shr1(ax); ax += dpp_shr2(ax); ax += dpp_shr4(ax); ax += dpp_shr8(ax);
        ay += dpp_shr1(ay); ay += dpp_shr2(ay); ay += dpp_shr4(ay); ay += dpp_shr8(ay);
        az += dpp_shr1(az); az += dpp_shr2(az); az += dpp_shr4(az); az += dpp_shr8(az);
        aw += dpp_shr1(aw); aw += dpp_shr2(aw); aw += dpp_shr4(aw); aw += dpp_shr8(aw);
        if (col == 15) {                 // rows 4q..4q+3 = x0+4q..x0+4q+3
            float4 o;
            o.x = 1.f / (1.f + __expf(-ax));
            o.y = 1.f / (1.f + __expf(-ay));
            o.z = 1.f / (1.f + __expf(-az));
            o.w = 1.f / (1.f + __expf(-aw));
            *(float4*)(p + (b << 18) + (zz << 12) + (y << 6) + x0 + 4 * q) = o;
        }
    }
}

// ============ fused propagation: in-place 48 KB LDS cube, compile-time T ======
// Cube 12z x 16y x 64x; output tile 4z x 8y x 64x (margins 4). Iteration it
// (lo=5-T+it) updates z,y in [lo, dim-lo); shrinking validity keeps it exact.
// 512 threads: bit 8 = z-half h. h=0 owns [lo,6) iterated TOP-DOWN (z=5-zi),
// h=1 owns [6,12-lo) bottom-up (z=6+zi) -> slot zi is h-independent and
// compile-time, so p/r are PRELOADED ONCE into registers (pv4/rv4[zi]) before
// the stage barrier and reused by all T iterations (removes the per-iteration
// L2-latency global loads that dominated). vn[] static-indexed throughout.
#define ZC 12
#define YC 16
#define PL 1024   // 16*64 floats per z-plane
#define ZMID 6

template<int T>
__global__ __launch_bounds__(512, 4) void prop_kernel(
    const float* __restrict__ vin, int sstride,
    const float* __restrict__ rimg,   // r base = img + 2^18, sample stride 2^19
    const float* __restrict__ pbuf,   // p, sample stride 2^18
    float* __restrict__ vout)
{
    __shared__ float S[ZC * PL];
    int blk = blockIdx.x;             // 512 blocks: b(4) x tz(16) x ty(8)
    int b  = blk >> 7;
    int tz = ((blk >> 3) & 15) << 2;
    int ty = (blk & 7) << 3;

    const float* vb = vin  + (size_t)b * sstride;
    const float* rb = rimg + ((size_t)b << 19);
    const float* pb = pbuf + ((size_t)b << 18);
    float*       ob = vout + ((size_t)b << 18);

    int tid  = threadIdx.x;
    int x4   = tid & 15, x0 = x4 << 2;
    int yy   = (tid >> 4) & 15;
    int h    = tid >> 8;              // z-half
    int lane = tid & 63;
    (void)lane;

    int gy = ty + yy - 4;
    bool vy = (unsigned)gy < 64u;

    int lbase = yy * 64 + x0;
    int goff  = gy * 64 + x0;

    const int z0 = h ? ZMID : (ZMID - 1);   // 6 or 5: iteration start plane
    const int d  = h ? 1 : -1;              // iteration direction

    // ---- stage: half h stages planes [6h, 6h+6)
    {
        const float* src = vb + gy * 64 + x0;
        #pragma unroll
        for (int zi = 0; zi < 6; ++zi) {
            int z  = 6 * h + zi;
            int gz = tz + z - 4;
            float4 v = make_float4(NEG_INF, NEG_INF, NEG_INF, NEG_INF);
            if (vy && ((unsigned)gz < 64u)) v = *(const float4*)(src + (gz << 12));
            *(float4*)(S + z * PL + yy * 64 + x0) = v;
        }
    }

    // ---- preload p/r for this thread's T+1 planes (latency hides under the
    // stage barrier; reused by every iteration). slot zi <-> plane z0 + d*zi.
    float4 pv4[5], rv4[5];
    #pragma unroll
    for (int zi = 0; zi < T + 1; ++zi) {
        int z  = z0 + d * zi;
        int gz = tz + z - 4;
        if (vy && ((unsigned)gz < 64u)) {
            int off = (gz << 12) + goff;
            pv4[zi] = *(const float4*)(pb + off);
            rv4[zi] = *(const float4*)(rb + off);
        }
    }
    __syncthreads();

    // ROWY: vertical 3-row max (float4) + horizontal 3-window via DPP shifts
    #define ROWY(zz_, Q, C) {                                                  \
        const float* pz = S + (zz_) * PL + lbase;                              \
        float4 r0 = *(const float4*)(pz - 64);                                 \
        float4 r1 = *(const float4*)(pz);                                      \
        float4 r2 = *(const float4*)(pz + 64);                                 \
        float4 cm;                                                             \
        cm.x = fmaxf(fmaxf(r0.x, r1.x), r2.x);                                 \
        cm.y = fmaxf(fmaxf(r0.y, r1.y), r2.y);                                 \
        cm.z = fmaxf(fmaxf(r0.z, r1.z), r2.z);                                 \
        cm.w = fmaxf(fmaxf(r0.w, r1.w), r2.w);                                 \
        float lm = dpp_shr1(cm.w);       /* lane i-1's cm.w */                 \
        float rm = dpp_shl1(cm.x);       /* lane i+1's cm.x */                 \
        if (x4 == 0)  lm = NEG_INF;                                            \
        if (x4 == 15) rm = NEG_INF;                                            \
        Q.x = fmaxf(lm, fmaxf(cm.x, cm.y));                                    \
        Q.y = fmaxf(cm.x, fmaxf(cm.y, cm.z));                                  \
        Q.z = fmaxf(cm.y, fmaxf(cm.z, cm.w));                                  \
        Q.w = fmaxf(fmaxf(cm.z, cm.w), rm);                                    \
        C = r1;                                                                \
    }

    #pragma unroll
    for (int it = 0; it < T; ++it) {
        const int lo   = 5 - T + it;
        const int span = ZMID - lo;          // T+1-it; same for both halves
        bool act = (yy >= lo) && (yy < YC - lo);
        float4 vn[5];
        if (act) {
            float4 qA, qB, qC, cB, cC, cd;
            ROWY(z0 - d, qA, cd);            // plane behind the start
            ROWY(z0,     qB, cB);
            #pragma unroll
            for (int zi = 0; zi < span; ++zi) {
                int z = z0 + d * zi;
                ROWY(z + d, qC, cC);
                int gz = tz + z - 4;
                float4 r;
                if (vy && ((unsigned)gz < 64u)) {
                    float4 pv = pv4[zi];
                    float4 rv = rv4[zi];
                    float4 m3;
                    m3.x = fmaxf(fmaxf(qA.x, qB.x), qC.x);
                    m3.y = fmaxf(fmaxf(qA.y, qB.y), qC.y);
                    m3.z = fmaxf(fmaxf(qA.z, qB.z), qC.z);
                    m3.w = fmaxf(fmaxf(qA.w, qB.w), qC.w);
                    r.x = fmaxf(cB.x, fmaf(pv.x, m3.x - rv.x, rv.x));
                    r.y = fmaxf(cB.y, fmaf(pv.y, m3.y - rv.y, rv.y));
                    r.z = fmaxf(cB.z, fmaf(pv.z, m3.z - rv.z, rv.z));
                    r.w = fmaxf(cB.w, fmaf(pv.w, m3.w - rv.w, rv.w));
                    if (it == T - 1) {
                        int off = (gz << 12) + goff;
                        *(float4*)(ob + off) = r;
                    }
                } else {
                    r = cB;    // out-of-volume stays -inf / stale
                }
                vn[zi] = r;
                qA = qB; qB = qC; cB = cC;
            }
        }
        __syncthreads();
        if (act) {
            #pragma unroll
            for (int zi = 0; zi < span; ++zi)
                *(float4*)(S + (z0 + d * zi) * PL + lbase) = vn[zi];
        }
        __syncthreads();
    }
    #undef ROWY
}

extern "C" void kernel_launch(void* const* d_in, const int* in_sizes, int n_in,
                              void* d_out, int out_size, void* d_ws, size_t ws_size,
                              hipStream_t stream) {
    const float* img = (const float*)d_in[0];   // (4,2,64,64,64)
    const float* hw  = (const float*)d_in[1];   // (150,27)
    const float* hb  = (const float*)d_in[2];   // (150,)
    const float* pw  = (const float*)d_in[3];   // (150,)
    // d_in[4] = k (device scalar); reference fixes k=30.

    float* out = (float*)d_out;                      // X buffer (4 MB)
    float* p   = (float*)d_ws;                       // 4 MB
    float* vA  = (float*)((char*)d_ws + (4u << 20)); // Y buffer (4 MB)
    // padded bf16 volume (2.3 MB) shares the vA slot: used only before prop #1
    unsigned short* pad = (unsigned short*)((char*)d_ws + (4u << 20));

    pad_kernel<<<dim3(1124, 4), 256, 0, stream>>>(img, pad);
    gate_mfma<<<4096, 256, 0, stream>>>(pad, hw, hb, pw, p);

    const float* r0 = img + (1 << 18);  // r channel base, sample stride 2^19

    // 7*T4 + 1*T2 = 30 iterations; ping-pong ends in d_out.
    prop_kernel<4><<<512, 512, 0, stream>>>(r0,  1 << 19, r0, p, vA);   // img -> Y
    prop_kernel<4><<<512, 512, 0, stream>>>(vA,  1 << 18, r0, p, out);  // Y -> X
    prop_kernel<4><<<512, 512, 0, stream>>>(out, 1 << 18, r0, p, vA);
    prop_kernel<4><<<512, 512, 0, stream>>>(vA,  1 << 18, r0, p, out);
    prop_kernel<4><<<512, 512, 0, stream>>>(out, 1 << 18, r0, p, vA);
    prop_kernel<4><<<512, 518 == 518 ? 512 : 512, 0, stream>>>(vA,  1 << 18, r0, p, out);
    prop_kernel<4><<<512, 512, 0, stream>>>(out, 1 << 18, r0, p, vA);
    prop_kernel<2><<<512, 512, 0, stream>>>(vA,  1 << 18, r0, p, out);  // -> d_out
}

// Round 7
// 179.398 us; speedup vs baseline: 1.2852x; 1.1327x over previous
//
#include <hip/hip_runtime.h>
#include <math.h>

#define NEG_INF (-__builtin_inff())

typedef __attribute__((ext_vector_type(8))) short short8;
typedef __attribute__((ext_vector_type(4))) float f32x4;

__device__ __forceinline__ unsigned f2bf(float f) {   // fp32 -> bf16 bits (RNE)
    union { float f; unsigned u; } v; v.f = f;
    return (v.u + 0x7fffu + ((v.u >> 16) & 1u)) >> 16;
}

// DPP row shifts within 16-lane rows. row_shr:n (0x110|n): lane i reads lane
// i-n within its 16-lane row; bound_ctrl=true -> out-of-row reads 0.
// VALU op: no DS pipe, no lgkm wait.
__device__ __forceinline__ float dpp_shr1(float x) {
    return __int_as_float(__builtin_amdgcn_update_dpp(
        0, __float_as_int(x), 0x111, 0xF, 0xF, true));
}
__device__ __forceinline__ float dpp_shr2(float x) {
    return __int_as_float(__builtin_amdgcn_update_dpp(
        0, __float_as_int(x), 0x112, 0xF, 0xF, true));
}
__device__ __forceinline__ float dpp_shr4(float x) {
    return __int_as_float(__builtin_amdgcn_update_dpp(
        0, __float_as_int(x), 0x114, 0xF, 0xF, true));
}
__device__ __forceinline__ float dpp_shr8(float x) {
    return __int_as_float(__builtin_amdgcn_update_dpp(
        0, __float_as_int(x), 0x118, 0xF, 0xF, true));
}
__device__ __forceinline__ float dpp_shl1(float x) {
    return __int_as_float(__builtin_amdgcn_update_dpp(
        0, __float_as_int(x), 0x101, 0xF, 0xF, true));
}

// ============ pad kernel: x channel -> zero-padded (4,66,66,66) bf16 ============
// Padded cell (z,y,x) = volume voxel (z-1,y-1,x-1); pad ring = 0 (conv SAME).
__global__ __launch_bounds__(256) void pad_kernel(
    const float* __restrict__ img, unsigned short* __restrict__ pad)
{
    int i = blockIdx.x * 256 + threadIdx.x;      // cell within one sample
    if (i >= 66 * 66 * 66) return;
    int b = blockIdx.y;
    int z = i / 4356;
    int rem = i - z * 4356;
    int y = rem / 66;
    int x = rem - y * 66;
    float v = 0.f;
    if (z >= 1 && z <= 64 && y >= 1 && y <= 64 && x >= 1 && x <= 64)
        v = img[((size_t)b << 19) + ((z - 1) << 12) + ((y - 1) << 6) + (x - 1)];
    pad[(size_t)b * 287496 + i] = (unsigned short)f2bf(v);
}

// ============ gate via MFMA (FROZEN from round 4 for clean prop A/B) ==========
__global__ __launch_bounds__(256, 4) void gate_mfma(
    const unsigned short* __restrict__ pad,
    const float* __restrict__ hw, const float* __restrict__ hb,
    const float* __restrict__ pw, float* __restrict__ p)
{
    __shared__ int4 Bsh[10 * 64];        // [t][lane] 16B fragments

    const int lane = threadIdx.x & 63;
    const int col  = lane & 15;          // B: channel-in-tile; A: voxel m
    const int q    = lane >> 4;
    const int wid  = threadIdx.x >> 6;
    const int W    = blockIdx.x * 4 + wid;   // 16384 waves; row = W

    // ---- build B tiles cooperatively: wave w builds t = w, w+4, w+8
    for (int t = wid; t < 10; t += 4) {
        int c = 16 * t + col;
        bool cv = c < 150;
        unsigned hv[8];
        #pragma unroll
        for (int j = 0; j < 8; ++j) {
            int k = 8 * q + j;
            float wv = 0.f;
            if (cv) {
                if (k < 27) wv = hw[c * 27 + k];
                else if (k == 27) wv = hb[c];
            }
            hv[j] = f2bf(wv);
        }
        Bsh[t * 64 + lane] = make_int4(hv[0] | (hv[1] << 16), hv[2] | (hv[3] << 16),
                                       hv[4] | (hv[5] << 16), hv[6] | (hv[7] << 16));
    }
    // ---- pw per lane (L1-resident after first wave)
    float pwv[10];
    #pragma unroll
    for (int t = 0; t < 10; ++t) {
        int c = 16 * t + col;
        pwv[t] = (c < 150) ? pw[c] : 0.f;
    }
    __syncthreads();

    int4 bfrag[10];
    #pragma unroll
    for (int t = 0; t < 10; ++t) bfrag[t] = Bsh[t * 64 + lane];

    // ---- per-lane A-tap offsets into padded volume (loop-invariant)
    int offL[8]; unsigned cstA[8]; bool ldA[8];
    #pragma unroll
    for (int j = 0; j < 8; ++j) {
        int k = 8 * q + j;
        int dz = (k * 57) >> 9;          // k/9 for k<32
        int rem = k - 9 * dz;
        int dy = (rem * 171) >> 9;       // rem/3
        int dx = rem - 3 * dy;
        ldA[j]  = (k < 27);
        offL[j] = (k < 27) ? (dz * 4356 + dy * 66 + dx) : 0;
        cstA[j] = (k == 27) ? 0x3F80u : 0u;   // bias row: bf16(1.0)
    }

    // ---- 4 groups of 16 voxels per wave: one full x-row (y=W&63)
    int y = W & 63, zz = (W >> 6) & 63, b = W >> 12;
    int rbase = b * 287496 + zz * 4356 + y * 66 + col;

    #pragma unroll 2
    for (int i = 0; i < 4; ++i) {
        int x0    = i << 4;
        int abase = rbase + x0;

        unsigned av[8];
        #pragma unroll
        for (int j = 0; j < 8; ++j) {
            unsigned v = pad[abase + offL[j]];
            av[j] = ldA[j] ? v : cstA[j];
        }
        union { int4 i4; short8 s8; } af, bfu;
        af.i4 = make_int4(av[0] | (av[1] << 16), av[2] | (av[3] << 16),
                          av[4] | (av[5] << 16), av[6] | (av[7] << 16));

        const f32x4 zero = {0.f, 0.f, 0.f, 0.f};
        f32x4 rr[10];
        #pragma unroll
        for (int t = 0; t < 10; ++t) {
            bfu.i4 = bfrag[t];
            rr[t] = __builtin_amdgcn_mfma_f32_16x16x32_bf16(af.s8, bfu.s8, zero, 0, 0, 0);
        }
        float ax = 0.f, ay = 0.f, az = 0.f, aw = 0.f;
        #pragma unroll
        for (int t = 0; t < 10; ++t) {
            ax = fmaf(pwv[t], fmaxf(rr[t].x, 0.f), ax);
            ay = fmaf(pwv[t], fmaxf(rr[t].y, 0.f), ay);
            az = fmaf(pwv[t], fmaxf(rr[t].z, 0.f), az);
            aw = fmaf(pwv[t], fmaxf(rr[t].w, 0.f), aw);
        }
        // sum across the 16 cols: DPP prefix-scan (shr 1,2,4,8); col 15 = total
        ax += dpp_shr1(ax); ax += dpp_shr2(ax); ax += dpp_shr4(ax); ax += dpp_shr8(ax);
        ay += dpp_shr1(ay); ay += dpp_shr2(ay); ay += dpp_shr4(ay); ay += dpp_shr8(ay);
        az += dpp_shr1(az); az += dpp_shr2(az); az += dpp_shr4(az); az += dpp_shr8(az);
        aw += dpp_shr1(aw); aw += dpp_shr2(aw); aw += dpp_shr4(aw); aw += dpp_shr8(aw);
        if (col == 15) {                 // rows 4q..4q+3 = x0+4q..x0+4q+3
            float4 o;
            o.x = 1.f / (1.f + __expf(-ax));
            o.y = 1.f / (1.f + __expf(-ay));
            o.z = 1.f / (1.f + __expf(-az));
            o.w = 1.f / (1.f + __expf(-aw));
            *(float4*)(p + (b << 18) + (zz << 12) + (y << 6) + x0 + 4 * q) = o;
        }
    }
}

// ============ fused propagation v3: v in REGISTERS, LDS holds reduced planes ==
// (identical to round-6 submission; that bench died on container acquisition,
// not on the kernel — re-audited: no divergent barriers, all indices bounded,
// validity chain [lo-1,16-lo] matches previous iteration's update range.)
// Tile 4z x 8y x 64x output, margins 4 (cube 12z x 16y x 64x). 512 threads:
// h = tid>>8 picks a z-half; thread owns 6 z-planes in registers with MIRRORED
// indexing (h0: v[zi]=plane zi; h1: v[zi]=plane 11-zi) so the active register
// range is [lo,6) for BOTH halves (all indices compile-time).
// Separable 3^3 max, reordered: z-max in REGISTERS, x-window via DPP, y-combine
// via LDS on the already x,z-reduced plane t. Per active plane: 1 t-write +
// 2 t-reads (vs 3 v-reads + 1 v-write before) and NO LDS staging of v at all:
// DS wave-ops/CU drop ~41% (the measured bottleneck). Cross-half z-neighbor via
// a 2-plane VEX exchange. LDS = 40KB t + 8KB VEX = 48KB -> 2 blocks/CU.
#define YC 16
#define PL 1024   // 16*64 floats per plane

template<int T>
__global__ __launch_bounds__(512, 4) void prop_kernel(
    const float* __restrict__ vin, int sstride,
    const float* __restrict__ rimg,   // r base = img + 2^18, sample stride 2^19
    const float* __restrict__ pbuf,   // p, sample stride 2^18
    float* __restrict__ vout)
{
    __shared__ float TL[10 * PL];     // t planes, slot = z-1 (z in [1,11))
    __shared__ float VEX[2 * PL];     // slot0: plane 5 (h0's), slot1: plane 6 (h1's)

    int blk = blockIdx.x;             // 512 blocks: b(4) x tz(16) x ty(8)
    int b  = blk >> 7;
    int tz = ((blk >> 3) & 15) << 2;
    int ty = (blk & 7) << 3;

    const float* vb = vin  + (size_t)b * sstride;
    const float* rb = rimg + ((size_t)b << 19);
    const float* pb = pbuf + ((size_t)b << 18);
    float*       ob = vout + ((size_t)b << 18);

    int tid  = threadIdx.x;
    int x4   = tid & 15, x0 = x4 << 2;
    int yy   = (tid >> 4) & 15;
    int h    = tid >> 8;              // z-half

    int gy = ty + yy - 4;
    bool vy = (unsigned)gy < 64u;
    int lbase = yy * 64 + x0;
    int goff  = gy * 64 + x0;

    // ---- load own half-column into registers (mirrored for h1)
    float4 v[6];
    #pragma unroll
    for (int zi = 0; zi < 6; ++zi) {
        int z  = h ? (11 - zi) : zi;
        int gz = tz + z - 4;
        float4 val = make_float4(NEG_INF, NEG_INF, NEG_INF, NEG_INF);
        if (vy && ((unsigned)gz < 64u)) val = *(const float4*)(vb + (gz << 12) + goff);
        v[zi] = val;
    }
    // boundary plane exchange: each half exposes its zi=5 (z=5 resp. z=6)
    *(float4*)(VEX + h * PL + lbase) = v[5];
    __syncthreads();

    #pragma unroll
    for (int it = 0; it < T; ++it) {
        const int lo = 5 - T + it;               // active zi in [lo,6)
        bool act_t = (yy >= lo - 1) && (yy < 17 - lo);
        bool act   = (yy >= lo) && (yy < YC - lo);

        // ---- phase A: z-max (regs) -> x-window (DPP) -> write t planes
        float4 vexN = *(const float4*)(VEX + (h ^ 1) * PL + lbase);
        float4 t[5];
        #pragma unroll
        for (int zi = lo; zi < 6; ++zi) {
            float4 za = v[zi - 1];
            float4 zb = v[zi];
            float4 zc = (zi == 5) ? vexN : v[zi + 1];
            float4 zm;
            zm.x = fmaxf(fmaxf(za.x, zb.x), zc.x);
            zm.y = fmaxf(fmaxf(za.y, zb.y), zc.y);
            zm.z = fmaxf(fmaxf(za.z, zb.z), zc.z);
            zm.w = fmaxf(fmaxf(za.w, zb.w), zc.w);
            float lm = dpp_shr1(zm.w);           // lane i-1's zm.w
            float rm = dpp_shl1(zm.x);           // lane i+1's zm.x
            if (x4 == 0)  lm = NEG_INF;
            if (x4 == 15) rm = NEG_INF;
            float4 tt;
            tt.x = fmaxf(lm, fmaxf(zm.x, zm.y));
            tt.y = fmaxf(zm.x, fmaxf(zm.y, zm.z));
            tt.z = fmaxf(zm.y, fmaxf(zm.z, zm.w));
            tt.w = fmaxf(fmaxf(zm.z, zm.w), rm);
            t[zi - lo] = tt;
            int z = h ? (11 - zi) : zi;          // slot z-1
            if (act_t) *(float4*)(TL + (z - 1) * PL + lbase) = tt;
        }
        __syncthreads();

        // ---- phase C: y-combine from LDS, update v in registers
        #pragma unroll
        for (int zi = lo; zi < 6; ++zi) {
            int z  = h ? (11 - zi) : zi;
            int gz = tz + z - 4;
            if (act) {
                const float* tp = TL + (z - 1) * PL + lbase;
                float4 tu = *(const float4*)(tp - 64);
                float4 td = *(const float4*)(tp + 64);
                float4 ts = t[zi - lo];
                float4 m3;
                m3.x = fmaxf(fmaxf(tu.x, td.x), ts.x);
                m3.y = fmaxf(fmaxf(tu.y, td.y), ts.y);
                m3.z = fmaxf(fmaxf(tu.z, td.z), ts.z);
                m3.w = fmaxf(fmaxf(tu.w, td.w), ts.w);
                if (vy && ((unsigned)gz < 64u)) {
                    int off = (gz << 12) + goff;
                    float4 pv = *(const float4*)(pb + off);
                    float4 rv = *(const float4*)(rb + off);
                    float4 nv;
                    nv.x = fmaxf(v[zi].x, fmaf(pv.x, m3.x - rv.x, rv.x));
                    nv.y = fmaxf(v[zi].y, fmaf(pv.y, m3.y - rv.y, rv.y));
                    nv.z = fmaxf(v[zi].z, fmaf(pv.z, m3.z - rv.z, rv.z));
                    nv.w = fmaxf(v[zi].w, fmaf(pv.w, m3.w - rv.w, rv.w));
                    v[zi] = nv;
                    if (it == T - 1) *(float4*)(ob + off) = nv;
                }
            }
        }
        // refresh boundary plane with this iteration's value
        *(float4*)(VEX + h * PL + lbase) = v[5];
        __syncthreads();
    }
}

extern "C" void kernel_launch(void* const* d_in, const int* in_sizes, int n_in,
                              void* d_out, int out_size, void* d_ws, size_t ws_size,
                              hipStream_t stream) {
    const float* img = (const float*)d_in[0];   // (4,2,64,64,64)
    const float* hw  = (const float*)d_in[1];   // (150,27)
    const float* hb  = (const float*)d_in[2];   // (150,)
    const float* pw  = (const float*)d_in[3];   // (150,)
    // d_in[4] = k (device scalar); reference fixes k=30.

    float* out = (float*)d_out;                      // X buffer (4 MB)
    float* p   = (float*)d_ws;                       // 4 MB
    float* vA  = (float*)((char*)d_ws + (4u << 20)); // Y buffer (4 MB)
    // padded bf16 volume (2.3 MB) shares the vA slot: used only before prop #1
    unsigned short* pad = (unsigned short*)((char*)d_ws + (4u << 20));

    pad_kernel<<<dim3(1124, 4), 256, 0, stream>>>(img, pad);
    gate_mfma<<<4096, 256, 0, stream>>>(pad, hw, hb, pw, p);

    const float* r0 = img + (1 << 18);  // r channel base, sample stride 2^19

    // 7*T4 + 1*T2 = 30 iterations; ping-pong ends in d_out.
    prop_kernel<4><<<512, 512, 0, stream>>>(r0,  1 << 19, r0, p, vA);   // img -> Y
    prop_kernel<4><<<512, 512, 0, stream>>>(vA,  1 << 18, r0, p, out);  // Y -> X
    prop_kernel<4><<<512, 512, 0, stream>>>(out, 1 << 18, r0, p, vA);
    prop_kernel<4><<<512, 512, 0, stream>>>(vA,  1 << 18, r0, p, out);
    prop_kernel<4><<<512, 512, 0, stream>>>(out, 1 << 18, r0, p, vA);
    prop_kernel<4><<<512, 512, 0, stream>>>(vA,  1 << 18, r0, p, out);
    prop_kernel<4><<<512, 512, 0, stream>>>(out, 1 << 18, r0, p, vA);
    prop_kernel<2><<<512, 512, 0, stream>>>(vA,  1 << 18, r0, p, out);  // -> d_out
}

// Round 8
// 178.998 us; speedup vs baseline: 1.2881x; 1.0022x over previous
//
#include <hip/hip_runtime.h>
#include <math.h>

#define NEG_INF (-__builtin_inff())

typedef __attribute__((ext_vector_type(8))) short short8;
typedef __attribute__((ext_vector_type(4))) float f32x4;

__device__ __forceinline__ unsigned f2bf(float f) {   // fp32 -> bf16 bits (RNE)
    union { float f; unsigned u; } v; v.f = f;
    return (v.u + 0x7fffu + ((v.u >> 16) & 1u)) >> 16;
}

// DPP row shifts within 16-lane rows. row_shr:n (0x110|n): lane i reads lane
// i-n within its 16-lane row; bound_ctrl=true -> out-of-row reads 0.
// VALU op: no DS pipe, no lgkm wait.
__device__ __forceinline__ float dpp_shr1(float x) {
    return __int_as_float(__builtin_amdgcn_update_dpp(
        0, __float_as_int(x), 0x111, 0xF, 0xF, true));
}
__device__ __forceinline__ float dpp_shr2(float x) {
    return __int_as_float(__builtin_amdgcn_update_dpp(
        0, __float_as_int(x), 0x112, 0xF, 0xF, true));
}
__device__ __forceinline__ float dpp_shr4(float x) {
    return __int_as_float(__builtin_amdgcn_update_dpp(
        0, __float_as_int(x), 0x114, 0xF, 0xF, true));
}
__device__ __forceinline__ float dpp_shr8(float x) {
    return __int_as_float(__builtin_amdgcn_update_dpp(
        0, __float_as_int(x), 0x118, 0xF, 0xF, true));
}
__device__ __forceinline__ float dpp_shl1(float x) {
    return __int_as_float(__builtin_amdgcn_update_dpp(
        0, __float_as_int(x), 0x101, 0xF, 0xF, true));
}

// ============ pad kernel: x channel -> zero-padded (4,66,66,66) bf16 ============
// Padded cell (z,y,x) = volume voxel (z-1,y-1,x-1); pad ring = 0 (conv SAME).
__global__ __launch_bounds__(256) void pad_kernel(
    const float* __restrict__ img, unsigned short* __restrict__ pad)
{
    int i = blockIdx.x * 256 + threadIdx.x;      // cell within one sample
    if (i >= 66 * 66 * 66) return;
    int b = blockIdx.y;
    int z = i / 4356;
    int rem = i - z * 4356;
    int y = rem / 66;
    int x = rem - y * 66;
    float v = 0.f;
    if (z >= 1 && z <= 64 && y >= 1 && y <= 64 && x >= 1 && x <= 64)
        v = img[((size_t)b << 19) + ((z - 1) << 12) + ((y - 1) << 6) + (x - 1)];
    pad[(size_t)b * 287496 + i] = (unsigned short)f2bf(v);
}

// ============ gate via MFMA (FROZEN from round 4) =============================
__global__ __launch_bounds__(256, 4) void gate_mfma(
    const unsigned short* __restrict__ pad,
    const float* __restrict__ hw, const float* __restrict__ hb,
    const float* __restrict__ pw, float* __restrict__ p)
{
    __shared__ int4 Bsh[10 * 64];        // [t][lane] 16B fragments

    const int lane = threadIdx.x & 63;
    const int col  = lane & 15;          // B: channel-in-tile; A: voxel m
    const int q    = lane >> 4;
    const int wid  = threadIdx.x >> 6;
    const int W    = blockIdx.x * 4 + wid;   // 16384 waves; row = W

    // ---- build B tiles cooperatively: wave w builds t = w, w+4, w+8
    for (int t = wid; t < 10; t += 4) {
        int c = 16 * t + col;
        bool cv = c < 150;
        unsigned hv[8];
        #pragma unroll
        for (int j = 0; j < 8; ++j) {
            int k = 8 * q + j;
            float wv = 0.f;
            if (cv) {
                if (k < 27) wv = hw[c * 27 + k];
                else if (k == 27) wv = hb[c];
            }
            hv[j] = f2bf(wv);
        }
        Bsh[t * 64 + lane] = make_int4(hv[0] | (hv[1] << 16), hv[2] | (hv[3] << 16),
                                       hv[4] | (hv[5] << 16), hv[6] | (hv[7] << 16));
    }
    // ---- pw per lane (L1-resident after first wave)
    float pwv[10];
    #pragma unroll
    for (int t = 0; t < 10; ++t) {
        int c = 16 * t + col;
        pwv[t] = (c < 150) ? pw[c] : 0.f;
    }
    __syncthreads();

    int4 bfrag[10];
    #pragma unroll
    for (int t = 0; t < 10; ++t) bfrag[t] = Bsh[t * 64 + lane];

    // ---- per-lane A-tap offsets into padded volume (loop-invariant)
    int offL[8]; unsigned cstA[8]; bool ldA[8];
    #pragma unroll
    for (int j = 0; j < 8; ++j) {
        int k = 8 * q + j;
        int dz = (k * 57) >> 9;          // k/9 for k<32
        int rem = k - 9 * dz;
        int dy = (rem * 171) >> 9;       // rem/3
        int dx = rem - 3 * dy;
        ldA[j]  = (k < 27);
        offL[j] = (k < 27) ? (dz * 4356 + dy * 66 + dx) : 0;
        cstA[j] = (k == 27) ? 0x3F80u : 0u;   // bias row: bf16(1.0)
    }

    // ---- 4 groups of 16 voxels per wave: one full x-row (y=W&63)
    int y = W & 63, zz = (W >> 6) & 63, b = W >> 12;
    int rbase = b * 287496 + zz * 4356 + y * 66 + col;

    #pragma unroll 2
    for (int i = 0; i < 4; ++i) {
        int x0    = i << 4;
        int abase = rbase + x0;

        unsigned av[8];
        #pragma unroll
        for (int j = 0; j < 8; ++j) {
            unsigned v = pad[abase + offL[j]];
            av[j] = ldA[j] ? v : cstA[j];
        }
        union { int4 i4; short8 s8; } af, bfu;
        af.i4 = make_int4(av[0] | (av[1] << 16), av[2] | (av[3] << 16),
                          av[4] | (av[5] << 16), av[6] | (av[7] << 16));

        const f32x4 zero = {0.f, 0.f, 0.f, 0.f};
        f32x4 rr[10];
        #pragma unroll
        for (int t = 0; t < 10; ++t) {
            bfu.i4 = bfrag[t];
            rr[t] = __builtin_amdgcn_mfma_f32_16x16x32_bf16(af.s8, bfu.s8, zero, 0, 0, 0);
        }
        float ax = 0.f, ay = 0.f, az = 0.f, aw = 0.f;
        #pragma unroll
        for (int t = 0; t < 10; ++t) {
            ax = fmaf(pwv[t], fmaxf(rr[t].x, 0.f), ax);
            ay = fmaf(pwv[t], fmaxf(rr[t].y, 0.f), ay);
            az = fmaf(pwv[t], fmaxf(rr[t].z, 0.f), az);
            aw = fmaf(pwv[t], fmaxf(rr[t].w, 0.f), aw);
        }
        // sum across the 16 cols: DPP prefix-scan (shr 1,2,4,8); col 15 = total
        ax += dpp_shr1(ax); ax += dpp_shr2(ax); ax += dpp_shr4(ax); ax += dpp_shr8(ax);
        ay += dpp_shr1(ay); ay += dpp_shr2(ay); ay += dpp_shr4(ay); ay += dpp_shr8(ay);
        az += dpp_shr1(az); az += dpp_shr2(az); az += dpp_shr4(az); az += dpp_shr8(az);
        aw += dpp_shr1(aw); aw += dpp_shr2(aw); aw += dpp_shr4(aw); aw += dpp_shr8(aw);
        if (col == 15) {                 // rows 4q..4q+3 = x0+4q..x0+4q+3
            float4 o;
            o.x = 1.f / (1.f + __expf(-ax));
            o.y = 1.f / (1.f + __expf(-ay));
            o.z = 1.f / (1.f + __expf(-az));
            o.w = 1.f / (1.f + __expf(-aw));
            *(float4*)(p + (b << 18) + (zz << 12) + (y << 6) + x0 + 4 * q) = o;
        }
    }
}

// ============ fused propagation v4: T=3, margin 3 (halo compounds ~quadratic
// with T; T=3 x 10 launches minimizes total halo work + per-launch fixed cost).
// Cube 10z x 14y x 64x, output 4z x 8y x 64x. 448 threads: h = (tid>=224)
// picks a z-half; thread owns 5 planes in registers, MIRRORED indexing
// (h0: v[zi]=plane zi; h1: v[zi]=plane 9-zi) -> active register range [lo,5)
// for both halves, all indices compile-time. Separable 3^3 max: z in regs,
// x via DPP, y via LDS on the x,z-reduced plane t (1 write + 2 reads each).
// Cross-half boundary via 2-plane VEX (both halves expose v[4] <-> planes 4,5).
// LDS = 28 KB TL + 7 KB VEX = 35 KB -> 2 blocks/CU (grid-bound), 14 waves/CU.
#define YC2 14
#define PL2 896    // 14*64 floats per plane
#define HALF 5     // planes per z-half

template<int T>    // instantiated with T=3; lo = 4 - T + it
__global__ __launch_bounds__(448, 3) void prop_kernel(
    const float* __restrict__ vin, int sstride,
    const float* __restrict__ rimg,   // r base = img + 2^18, sample stride 2^19
    const float* __restrict__ pbuf,   // p, sample stride 2^18
    float* __restrict__ vout)
{
    __shared__ float TL[8 * PL2];     // t planes, slot = z-1 (z in [1,9))
    __shared__ float VEX[2 * PL2];    // slot0: plane 4 (h0's), slot1: plane 5 (h1's)

    int blk = blockIdx.x;             // 512 blocks: b(4) x tz(16) x ty(8)
    int b  = blk >> 7;
    int tz = ((blk >> 3) & 15) << 2;
    int ty = (blk & 7) << 3;

    const float* vb = vin  + (size_t)b * sstride;
    const float* rb = rimg + ((size_t)b << 19);
    const float* pb = pbuf + ((size_t)b << 18);
    float*       ob = vout + ((size_t)b << 18);

    int tid  = threadIdx.x;
    int h    = (tid >= 224);          // z-half (16-lane rows stay (y,h)-uniform)
    int t2   = tid - h * 224;
    int x4   = t2 & 15, x0 = x4 << 2;
    int yy   = t2 >> 4;               // 0..13

    int gy = ty + yy - 3;
    bool vy = (unsigned)gy < 64u;
    int lbase = yy * 64 + x0;
    int goff  = gy * 64 + x0;

    // ---- load own half-column into registers (mirrored for h1)
    float4 v[HALF];
    #pragma unroll
    for (int zi = 0; zi < HALF; ++zi) {
        int z  = h ? (9 - zi) : zi;
        int gz = tz + z - 3;
        float4 val = make_float4(NEG_INF, NEG_INF, NEG_INF, NEG_INF);
        if (vy && ((unsigned)gz < 64u)) val = *(const float4*)(vb + (gz << 12) + goff);
        v[zi] = val;
    }
    // boundary plane exchange: each half exposes its zi=4 (plane 4 resp. 5)
    *(float4*)(VEX + h * PL2 + lbase) = v[HALF - 1];
    __syncthreads();

    #pragma unroll
    for (int it = 0; it < T; ++it) {
        const int lo = 4 - T + it;               // active zi in [lo,HALF)
        bool act_t = (yy >= lo - 1) && (yy < 15 - lo);
        bool act   = (yy >= lo) && (yy < YC2 - lo);

        // ---- phase A: z-max (regs) -> x-window (DPP) -> write t planes
        float4 vexN = *(const float4*)(VEX + (h ^ 1) * PL2 + lbase);
        float4 t[4];
        #pragma unroll
        for (int zi = lo; zi < HALF; ++zi) {
            float4 za = v[zi - 1];
            float4 zb = v[zi];
            float4 zc = (zi == HALF - 1) ? vexN : v[zi + 1];
            float4 zm;
            zm.x = fmaxf(fmaxf(za.x, zb.x), zc.x);
            zm.y = fmaxf(fmaxf(za.y, zb.y), zc.y);
            zm.z = fmaxf(fmaxf(za.z, zb.z), zc.z);
            zm.w = fmaxf(fmaxf(za.w, zb.w), zc.w);
            float lm = dpp_shr1(zm.w);           // lane i-1's zm.w
            float rm = dpp_shl1(zm.x);           // lane i+1's zm.x
            if (x4 == 0)  lm = NEG_INF;
            if (x4 == 15) rm = NEG_INF;
            float4 tt;
            tt.x = fmaxf(lm, fmaxf(zm.x, zm.y));
            tt.y = fmaxf(zm.x, fmaxf(zm.y, zm.z));
            tt.z = fmaxf(zm.y, fmaxf(zm.z, zm.w));
            tt.w = fmaxf(fmaxf(zm.z, zm.w), rm);
            t[zi - lo] = tt;
            int z = h ? (9 - zi) : zi;           // slot z-1
            if (act_t) *(float4*)(TL + (z - 1) * PL2 + lbase) = tt;
        }
        __syncthreads();

        // ---- phase C: y-combine from LDS, update v in registers
        #pragma unroll
        for (int zi = lo; zi < HALF; ++zi) {
            int z  = h ? (9 - zi) : zi;
            int gz = tz + z - 3;
            if (act) {
                const float* tp = TL + (z - 1) * PL2 + lbase;
                float4 tu = *(const float4*)(tp - 64);
                float4 td = *(const float4*)(tp + 64);
                float4 ts = t[zi - lo];
                float4 m3;
                m3.x = fmaxf(fmaxf(tu.x, td.x), ts.x);
                m3.y = fmaxf(fmaxf(tu.y, td.y), ts.y);
                m3.z = fmaxf(fmaxf(tu.z, td.z), ts.z);
                m3.w = fmaxf(fmaxf(tu.w, td.w), ts.w);
                if (vy && ((unsigned)gz < 64u)) {
                    int off = (gz << 12) + goff;
                    float4 pv = *(const float4*)(pb + off);
                    float4 rv = *(const float4*)(rb + off);
                    float4 nv;
                    nv.x = fmaxf(v[zi].x, fmaf(pv.x, m3.x - rv.x, rv.x));
                    nv.y = fmaxf(v[zi].y, fmaf(pv.y, m3.y - rv.y, rv.y));
                    nv.z = fmaxf(v[zi].z, fmaf(pv.z, m3.z - rv.z, rv.z));
                    nv.w = fmaxf(v[zi].w, fmaf(pv.w, m3.w - rv.w, rv.w));
                    v[zi] = nv;
                    if (it == T - 1) *(float4*)(ob + off) = nv;
                }
            }
        }
        // refresh boundary plane with this iteration's value
        *(float4*)(VEX + h * PL2 + lbase) = v[HALF - 1];
        __syncthreads();
    }
}

extern "C" void kernel_launch(void* const* d_in, const int* in_sizes, int n_in,
                              void* d_out, int out_size, void* d_ws, size_t ws_size,
                              hipStream_t stream) {
    const float* img = (const float*)d_in[0];   // (4,2,64,64,64)
    const float* hw  = (const float*)d_in[1];   // (150,27)
    const float* hb  = (const float*)d_in[2];   // (150,)
    const float* pw  = (const float*)d_in[3];   // (150,)
    // d_in[4] = k (device scalar); reference fixes k=30.

    float* out = (float*)d_out;                      // X buffer (4 MB)
    float* p   = (float*)d_ws;                       // 4 MB
    float* vA  = (float*)((char*)d_ws + (4u << 20)); // Y buffer (4 MB)
    // padded bf16 volume (2.3 MB) shares the vA slot: used only before prop #1
    unsigned short* pad = (unsigned short*)((char*)d_ws + (4u << 20));

    pad_kernel<<<dim3(1124, 4), 256, 0, stream>>>(img, pad);
    gate_mfma<<<4096, 256, 0, stream>>>(pad, hw, hb, pw, p);

    const float* r0 = img + (1 << 18);  // r channel base, sample stride 2^19

    // 10 * T3 = 30 iterations; ping-pong ends in d_out.
    prop_kernel<3><<<512, 448, 0, stream>>>(r0,  1 << 19, r0, p, vA);   // img -> Y
    prop_kernel<3><<<512, 448, 0, stream>>>(vA,  1 << 18, r0, p, out);  // Y -> X
    prop_kernel<3><<<512, 448, 0, stream>>>(out, 1 << 18, r0, p, vA);
    prop_kernel<3><<<512, 448, 0, stream>>>(vA,  1 << 18, r0, p, out);
    prop_kernel<3><<<512, 448, 0, stream>>>(out, 1 << 18, r0, p, vA);
    prop_kernel<3><<<512, 448, 0, stream>>>(vA,  1 << 18, r0, p, out);
    prop_kernel<3><<<512, 448, 0, stream>>>(out, 1 << 18, r0, p, vA);
    prop_kernel<3><<<512, 448, 0, stream>>>(vA,  1 << 18, r0, p, out);
    prop_kernel<3><<<512, 448, 0, stream>>>(out, 1 << 18, r0, p, vA);
    prop_kernel<3><<<512, 448, 0, stream>>>(vA,  1 << 18, r0, p, out);  // -> d_out
}